// Round 1
// baseline (790.638 us; speedup 1.0000x reference)
//
#include <hip/hip_runtime.h>

#define DM    1024
#define DFF   4096
#define SEQ   2048
#define BATCH 4
#define NROWS (BATCH * SEQ)   // 8192
#define HEADS 16
#define DKH   64

typedef __attribute__((ext_vector_type(4))) float          f32x4;
typedef __attribute__((ext_vector_type(8))) __bf16         bf16x8;
typedef __attribute__((ext_vector_type(8))) unsigned short u16x8;

static __device__ __forceinline__ unsigned short f2bf(float f) {
  unsigned u = __builtin_bit_cast(unsigned, f);
  u += 0x7fffu + ((u >> 16) & 1u);   // round-to-nearest-even
  return (unsigned short)(u >> 16);
}

// ---------------- fp32 -> bf16 weight conversion ----------------
__global__ void k_f2bf(const float* __restrict__ in, unsigned short* __restrict__ out, int n4) {
  int i = blockIdx.x * blockDim.x + threadIdx.x;
  if (i >= n4) return;
  float4 v = reinterpret_cast<const float4*>(in)[i];
  ushort4 o;
  o.x = f2bf(v.x); o.y = f2bf(v.y); o.z = f2bf(v.z); o.w = f2bf(v.w);
  reinterpret_cast<ushort4*>(out)[i] = o;
}

// ---------------- RMSNorm: fp32 in -> bf16 out ----------------
__global__ __launch_bounds__(256) void k_rmsnorm(const float* __restrict__ x,
                                                 const float* __restrict__ w,
                                                 unsigned short* __restrict__ out) {
  const int row = blockIdx.x;
  const float4 v = reinterpret_cast<const float4*>(x + (size_t)row * DM)[threadIdx.x];
  float ss = v.x * v.x + v.y * v.y + v.z * v.z + v.w * v.w;
#pragma unroll
  for (int off = 32; off > 0; off >>= 1) ss += __shfl_down(ss, off);
  __shared__ float red[4];
  if ((threadIdx.x & 63) == 0) red[threadIdx.x >> 6] = ss;
  __syncthreads();
  const float tot  = red[0] + red[1] + red[2] + red[3];
  const float rden = rsqrtf(tot * (1.0f / DM) + 1e-5f);
  const float4 wv = reinterpret_cast<const float4*>(w)[threadIdx.x];
  ushort4 o;
  o.x = f2bf(v.x * wv.x * rden);
  o.y = f2bf(v.y * wv.y * rden);
  o.z = f2bf(v.z * wv.z * rden);
  o.w = f2bf(v.w * wv.w * rden);
  reinterpret_cast<ushort4*>(out + (size_t)row * DM)[threadIdx.x] = o;
}

// ---------------- NT GEMM: C(MxN) = A(MxK,bf16) * B(NxK,bf16)^T ----------------
// EPI 0: C bf16.  EPI 1: C fp32 = acc + res.  EPI 2: C bf16 = gelu_erf(acc).
// 128x128 tile, 256 threads (4 waves), each wave 64x64 via 4x4 of 16x16x32 MFMA.
template <int EPI>
__global__ __launch_bounds__(256) void k_gemm_nt(const unsigned short* __restrict__ A,
                                                 const unsigned short* __restrict__ B,
                                                 void* __restrict__ Cv,
                                                 const float* __restrict__ res,
                                                 int M, int N, int K) {
  alignas(16) __shared__ unsigned short As[128 * 32];
  alignas(16) __shared__ unsigned short Bs[128 * 32];
  const int t  = threadIdx.x;
  const int w  = t >> 6;
  const int l  = t & 63;
  const int wr = w >> 1, wc = w & 1;
  const int lr = l & 15, lk = l >> 4;
  const int m0 = blockIdx.y * 128;
  const int n0 = blockIdx.x * 128;

  const int srow = t >> 2;        // 0..63
  const int scol = (t & 3) * 8;   // element col within 32-wide K-slab

  f32x4 acc[4][4] = {};

  for (int k0 = 0; k0 < K; k0 += 32) {
    __syncthreads();
#pragma unroll
    for (int r = 0; r < 2; ++r) {
      const unsigned short* ga = A + (size_t)(m0 + r * 64 + srow) * K + k0 + scol;
      const unsigned short* gb = B + (size_t)(n0 + r * 64 + srow) * K + k0 + scol;
      __builtin_amdgcn_global_load_lds((__attribute__((address_space(1))) void*)ga,
                                       (__attribute__((address_space(3))) void*)(As + r * 2048 + w * 512),
                                       16, 0, 0);
      __builtin_amdgcn_global_load_lds((__attribute__((address_space(1))) void*)gb,
                                       (__attribute__((address_space(3))) void*)(Bs + r * 2048 + w * 512),
                                       16, 0, 0);
    }
    __syncthreads();

    bf16x8 af[4], bf[4];
#pragma unroll
    for (int m = 0; m < 4; ++m)
      af[m] = *reinterpret_cast<const bf16x8*>(As + (wr * 64 + m * 16 + lr) * 32 + lk * 8);
#pragma unroll
    for (int n = 0; n < 4; ++n)
      bf[n] = *reinterpret_cast<const bf16x8*>(Bs + (wc * 64 + n * 16 + lr) * 32 + lk * 8);
#pragma unroll
    for (int m = 0; m < 4; ++m)
#pragma unroll
      for (int n = 0; n < 4; ++n)
        acc[m][n] = __builtin_amdgcn_mfma_f32_16x16x32_bf16(af[m], bf[n], acc[m][n], 0, 0, 0);
  }

#pragma unroll
  for (int m = 0; m < 4; ++m) {
#pragma unroll
    for (int n = 0; n < 4; ++n) {
#pragma unroll
      for (int r = 0; r < 4; ++r) {
        const size_t row = (size_t)(m0 + wr * 64 + m * 16 + lk * 4 + r);
        const size_t col = (size_t)(n0 + wc * 64 + n * 16 + lr);
        const float a = acc[m][n][r];
        if constexpr (EPI == 0) {
          ((unsigned short*)Cv)[row * N + col] = f2bf(a);
        } else if constexpr (EPI == 1) {
          ((float*)Cv)[row * N + col] = a + res[row * N + col];
        } else {
          const float g = 0.5f * a * (1.0f + erff(a * 0.70710678118f));
          ((unsigned short*)Cv)[row * N + col] = f2bf(g);
        }
      }
    }
  }
}

// ---------------- Flash causal attention ----------------
// grid (SEQ/64, HEADS, BATCH), 256 threads = 4 waves, wave w owns q rows [qbase+16w, +16).
// K-tiles of 32. S = Q K^T via MFMA (q layout: row=l&15), online softmax in regs,
// P bounced through per-wave LDS to A-fragment layout, PV via MFMA with V^T in LDS.
__global__ __launch_bounds__(256) void k_attn(const unsigned short* __restrict__ Q,
                                              const unsigned short* __restrict__ Kb,
                                              const unsigned short* __restrict__ Vb,
                                              unsigned short* __restrict__ O) {
  const int qt = blockIdx.x;
  const int h  = blockIdx.y;
  const int b  = blockIdx.z;
  const int t  = threadIdx.x, w = t >> 6, l = t & 63;
  const int lr = l & 15, lk = l >> 4;
  const int qbase   = qt * 64;
  const size_t rowB = (size_t)b * SEQ;
  const int hoff    = h * DKH;

  alignas(16) __shared__ unsigned short Ks[32][72];      // padded: 144B rows
  alignas(16) __shared__ unsigned short Vt[64][40];      // V^T, padded: 80B rows
  alignas(16) __shared__ unsigned short Pl[4][16][40];   // per-wave P bounce

  // Q fragments (held in registers for the whole block)
  bf16x8 qf[2];
  {
    const unsigned short* qp = Q + (rowB + qbase + w * 16 + lr) * DM + hoff + lk * 8;
    qf[0] = *reinterpret_cast<const bf16x8*>(qp);
    qf[1] = *reinterpret_cast<const bf16x8*>(qp + 32);
  }

  f32x4 oacc[4] = {};
  float mrun[4], lrun[4];
#pragma unroll
  for (int r = 0; r < 4; ++r) { mrun[r] = -1e30f; lrun[r] = 0.0f; }

  const int srow = t >> 3;        // 0..31
  const int scol = (t & 7) * 8;   // 0..56

  const int ktmax = (qbase + 63) >> 5;
  for (int kt = 0; kt <= ktmax; ++kt) {
    const int kbase = kt * 32;
    __syncthreads();
    // stage K tile (row-major) and V tile (transposed)
    u16x8 kv = *reinterpret_cast<const u16x8*>(Kb + (rowB + kbase + srow) * DM + hoff + scol);
    *reinterpret_cast<u16x8*>(&Ks[srow][scol]) = kv;
    u16x8 vv = *reinterpret_cast<const u16x8*>(Vb + (rowB + kbase + srow) * DM + hoff + scol);
#pragma unroll
    for (int i = 0; i < 8; ++i) Vt[scol + i][srow] = vv[i];
    __syncthreads();

    // S = Q K^T  (16q x 32k per wave)
    f32x4 sacc[2] = {};
#pragma unroll
    for (int kc = 0; kc < 2; ++kc)
#pragma unroll
      for (int kk = 0; kk < 2; ++kk) {
        bf16x8 kf = *reinterpret_cast<const bf16x8*>(&Ks[kc * 16 + lr][kk * 32 + lk * 8]);
        sacc[kc] = __builtin_amdgcn_mfma_f32_16x16x32_bf16(qf[kk], kf, sacc[kc], 0, 0, 0);
      }

    // scale + causal mask
    float S[2][4];
#pragma unroll
    for (int kc = 0; kc < 2; ++kc)
#pragma unroll
      for (int r = 0; r < 4; ++r) {
        const int qg = qbase + w * 16 + lk * 4 + r;
        const int kg = kbase + kc * 16 + lr;
        const float s = sacc[kc][r] * 0.125f;
        S[kc][r] = (kg > qg) ? -1e30f : s;
      }

    // online softmax per q-row (rows live on 16-lane groups)
#pragma unroll
    for (int r = 0; r < 4; ++r) {
      float tm = fmaxf(S[0][r], S[1][r]);
      tm = fmaxf(tm, __shfl_xor(tm, 1));
      tm = fmaxf(tm, __shfl_xor(tm, 2));
      tm = fmaxf(tm, __shfl_xor(tm, 4));
      tm = fmaxf(tm, __shfl_xor(tm, 8));
      const float mnew  = fmaxf(mrun[r], tm);
      const float alpha = __expf(mrun[r] - mnew);
      const float p0 = __expf(S[0][r] - mnew);
      const float p1 = __expf(S[1][r] - mnew);
      float ts = p0 + p1;
      ts += __shfl_xor(ts, 1);
      ts += __shfl_xor(ts, 2);
      ts += __shfl_xor(ts, 4);
      ts += __shfl_xor(ts, 8);
      lrun[r] = lrun[r] * alpha + ts;
      mrun[r] = mnew;
#pragma unroll
      for (int dn = 0; dn < 4; ++dn) oacc[dn][r] *= alpha;
      Pl[w][lk * 4 + r][lr]      = f2bf(p0);
      Pl[w][lk * 4 + r][16 + lr] = f2bf(p1);
    }
    asm volatile("" ::: "memory");  // order Pl stores before typed re-read below

    // PV: O += P(16x32) * V(32x64)
    bf16x8 pf = *reinterpret_cast<const bf16x8*>(&Pl[w][lr][lk * 8]);
#pragma unroll
    for (int dn = 0; dn < 4; ++dn) {
      bf16x8 vf = *reinterpret_cast<const bf16x8*>(&Vt[dn * 16 + lr][lk * 8]);
      oacc[dn] = __builtin_amdgcn_mfma_f32_16x16x32_bf16(pf, vf, oacc[dn], 0, 0, 0);
    }
  }

  // epilogue: O / l
#pragma unroll
  for (int dn = 0; dn < 4; ++dn)
#pragma unroll
    for (int r = 0; r < 4; ++r) {
      const int qg  = qbase + w * 16 + lk * 4 + r;
      const float v = oacc[dn][r] / lrun[r];
      O[(rowB + qg) * DM + hoff + dn * 16 + lr] = f2bf(v);
    }
}

// ---------------- launch ----------------
extern "C" void kernel_launch(void* const* d_in, const int* in_sizes, int n_in,
                              void* d_out, int out_size, void* d_ws, size_t ws_size,
                              hipStream_t stream) {
  const float* x   = (const float*)d_in[0];
  const float* ln1 = (const float*)d_in[1];
  const float* ln2 = (const float*)d_in[2];
  const float* wq  = (const float*)d_in[3];
  const float* wk  = (const float*)d_in[4];
  const float* wv  = (const float*)d_in[5];
  const float* wo  = (const float*)d_in[6];
  const float* w1  = (const float*)d_in[7];
  const float* w2  = (const float*)d_in[8];

  char* ws = (char*)d_ws;
  size_t off = 0;
  auto take = [&](size_t bytes) { void* p = ws + off; off += bytes; return p; };
  unsigned short* wqb = (unsigned short*)take((size_t)DM * DM * 2);
  unsigned short* wkb = (unsigned short*)take((size_t)DM * DM * 2);
  unsigned short* wvb = (unsigned short*)take((size_t)DM * DM * 2);
  unsigned short* wob = (unsigned short*)take((size_t)DM * DM * 2);
  unsigned short* w1b = (unsigned short*)take((size_t)DFF * DM * 2);
  unsigned short* w2b = (unsigned short*)take((size_t)DM * DFF * 2);
  unsigned short* xn  = (unsigned short*)take((size_t)NROWS * DM * 2);  // reused as attn-out
  unsigned short* qb  = (unsigned short*)take((size_t)NROWS * DM * 2);  // reused as yn
  unsigned short* kb  = (unsigned short*)take((size_t)NROWS * DM * 2);
  unsigned short* vb  = (unsigned short*)take((size_t)NROWS * DM * 2);
  float*          yb  = (float*)take((size_t)NROWS * DM * 4);
  unsigned short* hb  = (unsigned short*)take((size_t)NROWS * DFF * 2);

  auto cvt = [&](const float* src, unsigned short* dst, size_t n) {
    int n4 = (int)(n / 4);
    k_f2bf<<<dim3((n4 + 255) / 256), dim3(256), 0, stream>>>(src, dst, n4);
  };
  cvt(wq, wqb, (size_t)DM * DM);
  cvt(wk, wkb, (size_t)DM * DM);
  cvt(wv, wvb, (size_t)DM * DM);
  cvt(wo, wob, (size_t)DM * DM);
  cvt(w1, w1b, (size_t)DFF * DM);
  cvt(w2, w2b, (size_t)DM * DFF);

  k_rmsnorm<<<dim3(NROWS), dim3(256), 0, stream>>>(x, ln1, xn);

  const dim3 gD(DM / 128, NROWS / 128);    // (8, 64)
  k_gemm_nt<0><<<gD, dim3(256), 0, stream>>>(xn, wqb, qb, nullptr, NROWS, DM, DM);
  k_gemm_nt<0><<<gD, dim3(256), 0, stream>>>(xn, wkb, kb, nullptr, NROWS, DM, DM);
  k_gemm_nt<0><<<gD, dim3(256), 0, stream>>>(xn, wvb, vb, nullptr, NROWS, DM, DM);

  k_attn<<<dim3(SEQ / 64, HEADS, BATCH), dim3(256), 0, stream>>>(qb, kb, vb, xn);

  k_gemm_nt<1><<<gD, dim3(256), 0, stream>>>(xn, wob, yb, x, NROWS, DM, DM);

  k_rmsnorm<<<dim3(NROWS), dim3(256), 0, stream>>>(yb, ln2, qb);

  k_gemm_nt<2><<<dim3(DFF / 128, NROWS / 128), dim3(256), 0, stream>>>(qb, w1b, hb, nullptr, NROWS, DFF, DM);
  k_gemm_nt<1><<<gD, dim3(256), 0, stream>>>(hb, w2b, (float*)d_out, yb, NROWS, DM, DFF);
}

// Round 5
// 554.371 us; speedup vs baseline: 1.4262x; 1.4262x over previous
//
#include <hip/hip_runtime.h>

#define DM    1024
#define DFF   4096
#define SEQ   2048
#define BATCH 4
#define NROWS (BATCH * SEQ)   // 8192
#define HEADS 16
#define DKH   64

typedef __attribute__((ext_vector_type(4))) float          f32x4;
typedef __attribute__((ext_vector_type(8))) __bf16         bf16x8;
typedef __attribute__((ext_vector_type(8))) unsigned short u16x8;
typedef __attribute__((ext_vector_type(4))) unsigned short u16x4;

static __device__ __forceinline__ unsigned short f2bf(float f) {
  unsigned u = __builtin_bit_cast(unsigned, f);
  u += 0x7fffu + ((u >> 16) & 1u);   // round-to-nearest-even
  return (unsigned short)(u >> 16);
}

// ---------------- fp32 -> bf16 weight conversion ----------------
__global__ void k_f2bf(const float* __restrict__ in, unsigned short* __restrict__ out, int n4) {
  int i = blockIdx.x * blockDim.x + threadIdx.x;
  if (i >= n4) return;
  float4 v = reinterpret_cast<const float4*>(in)[i];
  ushort4 o;
  o.x = f2bf(v.x); o.y = f2bf(v.y); o.z = f2bf(v.z); o.w = f2bf(v.w);
  reinterpret_cast<ushort4*>(out)[i] = o;
}

// ---------------- RMSNorm: fp32 in -> bf16 out ----------------
__global__ __launch_bounds__(256) void k_rmsnorm(const float* __restrict__ x,
                                                 const float* __restrict__ w,
                                                 unsigned short* __restrict__ out) {
  const int row = blockIdx.x;
  const float4 v = reinterpret_cast<const float4*>(x + (size_t)row * DM)[threadIdx.x];
  float ss = v.x * v.x + v.y * v.y + v.z * v.z + v.w * v.w;
#pragma unroll
  for (int off = 32; off > 0; off >>= 1) ss += __shfl_down(ss, off);
  __shared__ float red[4];
  if ((threadIdx.x & 63) == 0) red[threadIdx.x >> 6] = ss;
  __syncthreads();
  const float tot  = red[0] + red[1] + red[2] + red[3];
  const float rden = rsqrtf(tot * (1.0f / DM) + 1e-5f);
  const float4 wv = reinterpret_cast<const float4*>(w)[threadIdx.x];
  ushort4 o;
  o.x = f2bf(v.x * wv.x * rden);
  o.y = f2bf(v.y * wv.y * rden);
  o.z = f2bf(v.z * wv.z * rden);
  o.w = f2bf(v.w * wv.w * rden);
  reinterpret_cast<ushort4*>(out + (size_t)row * DM)[threadIdx.x] = o;
}

// ---------------- bf16 transpose: VT[c][r] = V[r][c]  (NROWS x DM -> DM x NROWS) ----------------
__global__ __launch_bounds__(256) void k_vtrans(const unsigned short* __restrict__ V,
                                                unsigned short* __restrict__ VT) {
  __shared__ unsigned short Tl[64][65];   // +1 pad breaks bank conflicts
  const int t  = threadIdx.x;
  const int r0 = blockIdx.x * 64;         // token tile
  const int c0 = blockIdx.y * 64;         // d-model tile
  const int ltr = t >> 3;                 // 0..31
  const int lc  = (t & 7) * 8;
#pragma unroll
  for (int it = 0; it < 2; ++it) {
    const int r = ltr + 32 * it;
    u16x8 v = *reinterpret_cast<const u16x8*>(V + (size_t)(r0 + r) * DM + c0 + lc);
#pragma unroll
    for (int i = 0; i < 8; ++i) Tl[r][lc + i] = v[i];
  }
  __syncthreads();
#pragma unroll
  for (int it = 0; it < 2; ++it) {
    const int c = ltr + 32 * it;          // output row = d-model index within tile
    u16x8 o;
#pragma unroll
    for (int i = 0; i < 8; ++i) o[i] = Tl[lc + i][c];
    *reinterpret_cast<u16x8*>(VT + (size_t)(c0 + c) * NROWS + r0 + lc) = o;
  }
}

// ---------------- NT GEMM: C(MxN) = A(MxK,bf16) * B(NxK,bf16)^T ----------------
template <int EPI>
__global__ __launch_bounds__(256) void k_gemm_nt(const unsigned short* __restrict__ A,
                                                 const unsigned short* __restrict__ B,
                                                 void* __restrict__ Cv,
                                                 const float* __restrict__ res,
                                                 int M, int N, int K) {
  alignas(16) __shared__ unsigned short As[128 * 32];
  alignas(16) __shared__ unsigned short Bs[128 * 32];
  const int t  = threadIdx.x;
  const int w  = t >> 6;
  const int l  = t & 63;
  const int wr = w >> 1, wc = w & 1;
  const int lr = l & 15, lk = l >> 4;
  const int m0 = blockIdx.y * 128;
  const int n0 = blockIdx.x * 128;

  const int srow = t >> 2;
  const int scol = (t & 3) * 8;

  f32x4 acc[4][4] = {};

  for (int k0 = 0; k0 < K; k0 += 32) {
    __syncthreads();
#pragma unroll
    for (int r = 0; r < 2; ++r) {
      const unsigned short* ga = A + (size_t)(m0 + r * 64 + srow) * K + k0 + scol;
      const unsigned short* gb = B + (size_t)(n0 + r * 64 + srow) * K + k0 + scol;
      __builtin_amdgcn_global_load_lds((__attribute__((address_space(1))) void*)ga,
                                       (__attribute__((address_space(3))) void*)(As + r * 2048 + w * 512),
                                       16, 0, 0);
      __builtin_amdgcn_global_load_lds((__attribute__((address_space(1))) void*)gb,
                                       (__attribute__((address_space(3))) void*)(Bs + r * 2048 + w * 512),
                                       16, 0, 0);
    }
    __syncthreads();

    bf16x8 af[4], bf[4];
#pragma unroll
    for (int m = 0; m < 4; ++m)
      af[m] = *reinterpret_cast<const bf16x8*>(As + (wr * 64 + m * 16 + lr) * 32 + lk * 8);
#pragma unroll
    for (int n = 0; n < 4; ++n)
      bf[n] = *reinterpret_cast<const bf16x8*>(Bs + (wc * 64 + n * 16 + lr) * 32 + lk * 8);
#pragma unroll
    for (int m = 0; m < 4; ++m)
#pragma unroll
      for (int n = 0; n < 4; ++n)
        acc[m][n] = __builtin_amdgcn_mfma_f32_16x16x32_bf16(af[m], bf[n], acc[m][n], 0, 0, 0);
  }

#pragma unroll
  for (int m = 0; m < 4; ++m) {
#pragma unroll
    for (int n = 0; n < 4; ++n) {
#pragma unroll
      for (int r = 0; r < 4; ++r) {
        const size_t row = (size_t)(m0 + wr * 64 + m * 16 + lk * 4 + r);
        const size_t col = (size_t)(n0 + wc * 64 + n * 16 + lr);
        const float a = acc[m][n][r];
        if constexpr (EPI == 0) {
          ((unsigned short*)Cv)[row * N + col] = f2bf(a);
        } else if constexpr (EPI == 1) {
          ((float*)Cv)[row * N + col] = a + res[row * N + col];
        } else {
          const float g = 0.5f * a * (1.0f + erff(a * 0.70710678118f));
          ((unsigned short*)Cv)[row * N + col] = f2bf(g);
        }
      }
    }
  }
}

// ---------------- Flash causal attention (swapped QK^T, KVBLK=64) ----------------
// grid (SEQ/128, HEADS, BATCH), 256 threads = 4 waves.
// Wave w owns q rows [qt*128 + 32w, +32) as two 16-row groups g=0,1.
// S^T = mfma(K, Q): lane (lr,lk) reg r holds S[k=16t+4lk+r][q=lr] -> softmax is
// lane-local over 16 vals + 2 shfl_xor. P bounced through swizzled per-wave LDS
// (compiler barrier before the TBAA-distinct re-read). K and V^T staged via
// global_load_lds with pre-swizzled global source. NOTE: one global_load_lds
// moves exactly 64 lanes x 16B = 1024B; each wave's 2048B region needs TWO
// loads per buffer (rounds 3-4 failed by staging only half the tile).
__global__ __launch_bounds__(256) void k_attn(const unsigned short* __restrict__ Q,
                                              const unsigned short* __restrict__ Kb,
                                              const unsigned short* __restrict__ VT,
                                              unsigned short* __restrict__ O) {
  const int qt = (int)gridDim.x - 1 - (int)blockIdx.x;   // longest blocks first
  const int h  = blockIdx.y;
  const int b  = blockIdx.z;
  const int t  = threadIdx.x, w = t >> 6, l = t & 63;
  const int lr = l & 15, lk = l >> 4;
  const int qbase = qt * 128;
  const int qw    = qbase + 32 * w;
  const size_t rowB = (size_t)b * SEQ;
  const int hoff  = h * DKH;

  // Ks: [64 k][64 dk] rows of 128B, 16B-granule slot = g ^ (k&7)
  alignas(16) __shared__ unsigned short Ks[64 * 64];
  // Vt: [64 d][64 k] rows of 128B, granule slot = g ^ (d&7)
  alignas(16) __shared__ unsigned short Vt[64 * 64];
  // P bounce per wave: [32 q][64 k], 16B granules XOR 16*(q&7)
  alignas(16) __shared__ unsigned short Ps[4][32 * 64];

  char* const KsB = (char*)Ks;
  char* const VtB = (char*)Vt;
  char* const PsB = (char*)(Ps[w]);

  // Q fragments (registers for the whole block): lane lr -> q row, lk -> dk chunk
  bf16x8 qf[2][2];
#pragma unroll
  for (int g = 0; g < 2; ++g)
#pragma unroll
    for (int kk = 0; kk < 2; ++kk)
      qf[g][kk] = *reinterpret_cast<const bf16x8*>(
          Q + (rowB + qw + 16 * g + lr) * DM + hoff + 32 * kk + 8 * lk);

  f32x4 oacc[2][4] = {};
  float mrun[2] = {-1e30f, -1e30f};
  float lrun[2] = {0.0f, 0.0f};

  const int ktmax = (qbase + 127) >> 6;
  for (int kt = 0; kt <= ktmax; ++kt) {
    const int kbase = kt * 64;
    __syncthreads();
#pragma unroll
    for (int half = 0; half < 2; ++half) {
      const int srow = w * 16 + half * 8 + (l >> 3);   // LDS row this lane covers
      const int sgr  = (l & 7) ^ (srow & 7);           // pre-swizzled source granule
      const unsigned short* gk = Kb + (rowB + kbase + srow) * DM + hoff + 8 * sgr;
      __builtin_amdgcn_global_load_lds((__attribute__((address_space(1))) void*)gk,
                                       (__attribute__((address_space(3))) void*)(KsB + w * 2048 + half * 1024),
                                       16, 0, 0);
      const unsigned short* gv = VT + (size_t)(hoff + srow) * NROWS + rowB + kbase + 8 * sgr;
      __builtin_amdgcn_global_load_lds((__attribute__((address_space(1))) void*)gv,
                                       (__attribute__((address_space(3))) void*)(VtB + w * 2048 + half * 1024),
                                       16, 0, 0);
    }
    __syncthreads();

    if (kbase > qw + 31) continue;   // fully masked for this wave; barriers balanced

    // ---- QK^T: S^T[k][q], 64k x 16q per group ----
    f32x4 sacc[2][4] = {};
#pragma unroll
    for (int tt = 0; tt < 4; ++tt) {
      bf16x8 kf0 = *reinterpret_cast<const bf16x8*>(KsB + (16 * tt + lr) * 128 + 16 * ((lk + 0) ^ (lr & 7)));
      bf16x8 kf1 = *reinterpret_cast<const bf16x8*>(KsB + (16 * tt + lr) * 128 + 16 * ((lk + 4) ^ (lr & 7)));
#pragma unroll
      for (int g = 0; g < 2; ++g) {
        sacc[g][tt] = __builtin_amdgcn_mfma_f32_16x16x32_bf16(kf0, qf[g][0], sacc[g][tt], 0, 0, 0);
        sacc[g][tt] = __builtin_amdgcn_mfma_f32_16x16x32_bf16(kf1, qf[g][1], sacc[g][tt], 0, 0, 0);
      }
    }

    // ---- softmax per q-group, pack P into LDS ----
#pragma unroll
    for (int g = 0; g < 2; ++g) {
      const int qg = qw + 16 * g + lr;
      float s[4][4];
      if (kbase + 63 > qw + 16 * g) {
#pragma unroll
        for (int tt = 0; tt < 4; ++tt)
#pragma unroll
          for (int r = 0; r < 4; ++r) {
            const int kg = kbase + 16 * tt + 4 * lk + r;
            s[tt][r] = (kg > qg) ? -1e30f : sacc[g][tt][r] * 0.125f;
          }
      } else {
#pragma unroll
        for (int tt = 0; tt < 4; ++tt)
#pragma unroll
          for (int r = 0; r < 4; ++r) s[tt][r] = sacc[g][tt][r] * 0.125f;
      }
      float tm = s[0][0];
#pragma unroll
      for (int tt = 0; tt < 4; ++tt)
#pragma unroll
        for (int r = 0; r < 4; ++r) tm = fmaxf(tm, s[tt][r]);
      tm = fmaxf(tm, __shfl_xor(tm, 16));
      tm = fmaxf(tm, __shfl_xor(tm, 32));
      const float mnew  = fmaxf(mrun[g], tm);
      const float alpha = __expf(mrun[g] - mnew);
      mrun[g] = mnew;
      float ts = 0.0f;
      unsigned short pb[4][4];
#pragma unroll
      for (int tt = 0; tt < 4; ++tt)
#pragma unroll
        for (int r = 0; r < 4; ++r) {
          const float p = __expf(s[tt][r] - mnew);
          ts += p;
          pb[tt][r] = f2bf(p);
        }
      ts += __shfl_xor(ts, 16);
      ts += __shfl_xor(ts, 32);
      lrun[g] = lrun[g] * alpha + ts;
#pragma unroll
      for (int r = 0; r < 4; ++r) {
        const float ar = __shfl(alpha, 4 * lk + r);
#pragma unroll
        for (int dn = 0; dn < 4; ++dn) oacc[g][dn][r] *= ar;
      }
#pragma unroll
      for (int tt = 0; tt < 4; ++tt) {
        u16x4 pw = {pb[tt][0], pb[tt][1], pb[tt][2], pb[tt][3]};
        *reinterpret_cast<u16x4*>(
            PsB + (16 * g + lr) * 128 + ((32 * tt + 8 * lk) ^ (16 * (lr & 7)))) = pw;
      }
    }

    // order P stores before the TBAA-distinct typed re-read below
    asm volatile("" ::: "memory");

    // ---- PV: O[q][d] += P[q][k] V[k][d] ----
#pragma unroll
    for (int kk = 0; kk < 2; ++kk) {
      bf16x8 pa[2];
#pragma unroll
      for (int g = 0; g < 2; ++g)
        pa[g] = *reinterpret_cast<const bf16x8*>(
            PsB + (16 * g + lr) * 128 + ((64 * kk + 16 * lk) ^ (16 * (lr & 7))));
#pragma unroll
      for (int dn = 0; dn < 4; ++dn) {
        bf16x8 vf = *reinterpret_cast<const bf16x8*>(
            VtB + (16 * dn + lr) * 128 + 16 * ((4 * kk + lk) ^ (lr & 7)));
        oacc[0][dn] = __builtin_amdgcn_mfma_f32_16x16x32_bf16(pa[0], vf, oacc[0][dn], 0, 0, 0);
        oacc[1][dn] = __builtin_amdgcn_mfma_f32_16x16x32_bf16(pa[1], vf, oacc[1][dn], 0, 0, 0);
      }
    }
  }

  // ---- epilogue: O / l ----
#pragma unroll
  for (int g = 0; g < 2; ++g) {
#pragma unroll
    for (int r = 0; r < 4; ++r) {
      const float li = 1.0f / __shfl(lrun[g], 4 * lk + r);
      const size_t row = rowB + qw + 16 * g + 4 * lk + r;
#pragma unroll
      for (int dn = 0; dn < 4; ++dn)
        O[row * DM + hoff + 16 * dn + lr] = f2bf(oacc[g][dn][r] * li);
    }
  }
}

// ---------------- launch ----------------
extern "C" void kernel_launch(void* const* d_in, const int* in_sizes, int n_in,
                              void* d_out, int out_size, void* d_ws, size_t ws_size,
                              hipStream_t stream) {
  const float* x   = (const float*)d_in[0];
  const float* ln1 = (const float*)d_in[1];
  const float* ln2 = (const float*)d_in[2];
  const float* wq  = (const float*)d_in[3];
  const float* wk  = (const float*)d_in[4];
  const float* wv  = (const float*)d_in[5];
  const float* wo  = (const float*)d_in[6];
  const float* w1  = (const float*)d_in[7];
  const float* w2  = (const float*)d_in[8];

  char* ws = (char*)d_ws;
  size_t off = 0;
  auto take = [&](size_t bytes) { void* p = ws + off; off += bytes; return p; };
  unsigned short* wqb = (unsigned short*)take((size_t)DM * DM * 2);
  unsigned short* wkb = (unsigned short*)take((size_t)DM * DM * 2);
  unsigned short* wvb = (unsigned short*)take((size_t)DM * DM * 2);
  unsigned short* wob = (unsigned short*)take((size_t)DM * DM * 2);
  unsigned short* w1b = (unsigned short*)take((size_t)DFF * DM * 2);
  unsigned short* w2b = (unsigned short*)take((size_t)DM * DFF * 2);
  unsigned short* xn  = (unsigned short*)take((size_t)NROWS * DM * 2);  // reused as attn-out
  unsigned short* qb  = (unsigned short*)take((size_t)NROWS * DM * 2);  // reused as yn
  unsigned short* kb  = (unsigned short*)take((size_t)NROWS * DM * 2);
  unsigned short* vb  = (unsigned short*)take((size_t)NROWS * DM * 2);
  float*          yb  = (float*)take((size_t)NROWS * DM * 4);
  unsigned short* hb  = (unsigned short*)take((size_t)NROWS * DFF * 2);
  unsigned short* vtb = hb;   // V^T [DM][NROWS] (16 MB) aliases FFN scratch: attn
                              // finishes before the FFN h-GEMM writes hb.

  auto cvt = [&](const float* src, unsigned short* dst, size_t n) {
    int n4 = (int)(n / 4);
    k_f2bf<<<dim3((n4 + 255) / 256), dim3(256), 0, stream>>>(src, dst, n4);
  };
  cvt(wq, wqb, (size_t)DM * DM);
  cvt(wk, wkb, (size_t)DM * DM);
  cvt(wv, wvb, (size_t)DM * DM);
  cvt(wo, wob, (size_t)DM * DM);
  cvt(w1, w1b, (size_t)DFF * DM);
  cvt(w2, w2b, (size_t)DM * DFF);

  k_rmsnorm<<<dim3(NROWS), dim3(256), 0, stream>>>(x, ln1, xn);

  const dim3 gD(DM / 128, NROWS / 128);    // (8, 64)
  k_gemm_nt<0><<<gD, dim3(256), 0, stream>>>(xn, wqb, qb, nullptr, NROWS, DM, DM);
  k_gemm_nt<0><<<gD, dim3(256), 0, stream>>>(xn, wkb, kb, nullptr, NROWS, DM, DM);
  k_gemm_nt<0><<<gD, dim3(256), 0, stream>>>(xn, wvb, vb, nullptr, NROWS, DM, DM);

  k_vtrans<<<dim3(NROWS / 64, DM / 64), dim3(256), 0, stream>>>(vb, vtb);

  k_attn<<<dim3(SEQ / 128, HEADS, BATCH), dim3(256), 0, stream>>>(qb, kb, vtb, xn);

  k_gemm_nt<1><<<gD, dim3(256), 0, stream>>>(xn, wob, yb, x, NROWS, DM, DM);

  k_rmsnorm<<<dim3(NROWS), dim3(256), 0, stream>>>(yb, ln2, qb);

  k_gemm_nt<2><<<dim3(DFF / 128, NROWS / 128), dim3(256), 0, stream>>>(qb, w1b, hb, nullptr, NROWS, DFF, DM);
  k_gemm_nt<1><<<gD, dim3(256), 0, stream>>>(hb, w2b, (float*)d_out, yb, NROWS, DM, DFF);
}

// Round 6
// 528.410 us; speedup vs baseline: 1.4963x; 1.0491x over previous
//
#include <hip/hip_runtime.h>

#define DM    1024
#define DFF   4096
#define SEQ   2048
#define BATCH 4
#define NROWS (BATCH * SEQ)   // 8192
#define HEADS 16
#define DKH   64
#define QSTR  (3 * DM)        // fused QKV row stride

typedef __attribute__((ext_vector_type(4))) float          f32x4;
typedef __attribute__((ext_vector_type(8))) __bf16         bf16x8;
typedef __attribute__((ext_vector_type(8))) unsigned short u16x8;
typedef __attribute__((ext_vector_type(4))) unsigned short u16x4;

static __device__ __forceinline__ unsigned short f2bf(float f) {
  unsigned u = __builtin_bit_cast(unsigned, f);
  u += 0x7fffu + ((u >> 16) & 1u);   // round-to-nearest-even
  return (unsigned short)(u >> 16);
}

// ---------------- fp32 -> bf16 weight conversion ----------------
__global__ void k_f2bf(const float* __restrict__ in, unsigned short* __restrict__ out, int n4) {
  int i = blockIdx.x * blockDim.x + threadIdx.x;
  if (i >= n4) return;
  float4 v = reinterpret_cast<const float4*>(in)[i];
  ushort4 o;
  o.x = f2bf(v.x); o.y = f2bf(v.y); o.z = f2bf(v.z); o.w = f2bf(v.w);
  reinterpret_cast<ushort4*>(out)[i] = o;
}

// ---------------- RMSNorm: fp32 in -> bf16 out ----------------
__global__ __launch_bounds__(256) void k_rmsnorm(const float* __restrict__ x,
                                                 const float* __restrict__ w,
                                                 unsigned short* __restrict__ out) {
  const int row = blockIdx.x;
  const float4 v = reinterpret_cast<const float4*>(x + (size_t)row * DM)[threadIdx.x];
  float ss = v.x * v.x + v.y * v.y + v.z * v.z + v.w * v.w;
#pragma unroll
  for (int off = 32; off > 0; off >>= 1) ss += __shfl_down(ss, off);
  __shared__ float red[4];
  if ((threadIdx.x & 63) == 0) red[threadIdx.x >> 6] = ss;
  __syncthreads();
  const float tot  = red[0] + red[1] + red[2] + red[3];
  const float rden = rsqrtf(tot * (1.0f / DM) + 1e-5f);
  const float4 wv = reinterpret_cast<const float4*>(w)[threadIdx.x];
  ushort4 o;
  o.x = f2bf(v.x * wv.x * rden);
  o.y = f2bf(v.y * wv.y * rden);
  o.z = f2bf(v.z * wv.z * rden);
  o.w = f2bf(v.w * wv.w * rden);
  reinterpret_cast<ushort4*>(out + (size_t)row * DM)[threadIdx.x] = o;
}

// ---------------- bf16 transpose: VT[c][r] = V[r][c] (strided src) ----------------
__global__ __launch_bounds__(256) void k_vtrans(const unsigned short* __restrict__ V, int vstr,
                                                unsigned short* __restrict__ VT) {
  __shared__ unsigned short Tl[64][65];   // +1 pad breaks bank conflicts
  const int t  = threadIdx.x;
  const int r0 = blockIdx.x * 64;         // token tile
  const int c0 = blockIdx.y * 64;         // d-model tile
  const int ltr = t >> 3;                 // 0..31
  const int lc  = (t & 7) * 8;
#pragma unroll
  for (int it = 0; it < 2; ++it) {
    const int r = ltr + 32 * it;
    u16x8 v = *reinterpret_cast<const u16x8*>(V + (size_t)(r0 + r) * vstr + c0 + lc);
#pragma unroll
    for (int i = 0; i < 8; ++i) Tl[r][lc + i] = v[i];
  }
  __syncthreads();
#pragma unroll
  for (int it = 0; it < 2; ++it) {
    const int c = ltr + 32 * it;
    u16x8 o;
#pragma unroll
    for (int i = 0; i < 8; ++i) o[i] = Tl[lc + i][c];
    *reinterpret_cast<u16x8*>(VT + (size_t)(c0 + c) * NROWS + r0 + lc) = o;
  }
}

// ---------------- NT GEMM: C(MxN) = A(MxK,bf16) * B(NxK,bf16)^T ----------------
template <int EPI>
__global__ __launch_bounds__(256) void k_gemm_nt(const unsigned short* __restrict__ A,
                                                 const unsigned short* __restrict__ B,
                                                 void* __restrict__ Cv,
                                                 const float* __restrict__ res,
                                                 int M, int N, int K) {
  alignas(16) __shared__ unsigned short As[128 * 32];
  alignas(16) __shared__ unsigned short Bs[128 * 32];
  const int t  = threadIdx.x;
  const int w  = t >> 6;
  const int l  = t & 63;
  const int wr = w >> 1, wc = w & 1;
  const int lr = l & 15, lk = l >> 4;
  const int m0 = blockIdx.y * 128;
  const int n0 = blockIdx.x * 128;

  const int srow = t >> 2;
  const int scol = (t & 3) * 8;

  f32x4 acc[4][4] = {};

  for (int k0 = 0; k0 < K; k0 += 32) {
    __syncthreads();
#pragma unroll
    for (int r = 0; r < 2; ++r) {
      const unsigned short* ga = A + (size_t)(m0 + r * 64 + srow) * K + k0 + scol;
      const unsigned short* gb = B + (size_t)(n0 + r * 64 + srow) * K + k0 + scol;
      __builtin_amdgcn_global_load_lds((__attribute__((address_space(1))) void*)ga,
                                       (__attribute__((address_space(3))) void*)(As + r * 2048 + w * 512),
                                       16, 0, 0);
      __builtin_amdgcn_global_load_lds((__attribute__((address_space(1))) void*)gb,
                                       (__attribute__((address_space(3))) void*)(Bs + r * 2048 + w * 512),
                                       16, 0, 0);
    }
    __syncthreads();

    bf16x8 af[4], bf[4];
#pragma unroll
    for (int m = 0; m < 4; ++m)
      af[m] = *reinterpret_cast<const bf16x8*>(As + (wr * 64 + m * 16 + lr) * 32 + lk * 8);
#pragma unroll
    for (int n = 0; n < 4; ++n)
      bf[n] = *reinterpret_cast<const bf16x8*>(Bs + (wc * 64 + n * 16 + lr) * 32 + lk * 8);
#pragma unroll
    for (int m = 0; m < 4; ++m)
#pragma unroll
      for (int n = 0; n < 4; ++n)
        acc[m][n] = __builtin_amdgcn_mfma_f32_16x16x32_bf16(af[m], bf[n], acc[m][n], 0, 0, 0);
  }

#pragma unroll
  for (int m = 0; m < 4; ++m) {
#pragma unroll
    for (int n = 0; n < 4; ++n) {
#pragma unroll
      for (int r = 0; r < 4; ++r) {
        const size_t row = (size_t)(m0 + wr * 64 + m * 16 + lk * 4 + r);
        const size_t col = (size_t)(n0 + wc * 64 + n * 16 + lr);
        const float a = acc[m][n][r];
        if constexpr (EPI == 0) {
          ((unsigned short*)Cv)[row * N + col] = f2bf(a);
        } else if constexpr (EPI == 1) {
          ((float*)Cv)[row * N + col] = a + res[row * N + col];
        } else {
          const float g = 0.5f * a * (1.0f + erff(a * 0.70710678118f));
          ((unsigned short*)Cv)[row * N + col] = f2bf(g);
        }
      }
    }
  }
}

// ---------------- Flash causal attention (swapped QK^T, KVBLK=64, dbuf K/V) ----------------
// grid (SEQ/128, HEADS, BATCH), 256 threads = 4 waves.
// Q and K come from the fused QKV buffer (row stride QSTR; K at column offset DM).
// 2-phase pipeline: prefetch tile t+1 via global_load_lds right after the barrier,
// compute tile t from the other buffer; next iteration's barrier (vmcnt drain)
// is the only wait. P bounced through swizzled per-wave LDS (compiler barrier
// before the TBAA-distinct re-read). One global_load_lds = 1024B/wave, so each
// wave's 2048B tile region takes TWO loads per buffer.
__global__ __launch_bounds__(256) void k_attn(const unsigned short* __restrict__ QKV,
                                              const unsigned short* __restrict__ VT,
                                              unsigned short* __restrict__ O) {
  const int qt = (int)gridDim.x - 1 - (int)blockIdx.x;   // longest blocks first
  const int h  = blockIdx.y;
  const int b  = blockIdx.z;
  const int t  = threadIdx.x, w = t >> 6, l = t & 63;
  const int lr = l & 15, lk = l >> 4;
  const int qbase = qt * 128;
  const int qw    = qbase + 32 * w;
  const size_t rowB = (size_t)b * SEQ;
  const int hoff  = h * DKH;

  // double-buffered: Ks/Vt [2][64 rows][128B], 16B-granule slot = g ^ (row&7)
  alignas(16) __shared__ unsigned short Ks[2][64 * 64];
  alignas(16) __shared__ unsigned short Vt[2][64 * 64];
  // P bounce per wave: [32 q][64 k], 16B granules XOR 16*(q&7)
  alignas(16) __shared__ unsigned short Ps[4][32 * 64];

  char* const KsB = (char*)Ks;
  char* const VtB = (char*)Vt;
  char* const PsB = (char*)(Ps[w]);

  auto stage = [&](int buf, int kb2) {
#pragma unroll
    for (int half = 0; half < 2; ++half) {
      const int srow = w * 16 + half * 8 + (l >> 3);
      const int sgr  = (l & 7) ^ (srow & 7);   // pre-swizzled source granule
      const unsigned short* gk = QKV + (size_t)(rowB + kb2 + srow) * QSTR + DM + hoff + 8 * sgr;
      __builtin_amdgcn_global_load_lds((__attribute__((address_space(1))) void*)gk,
                                       (__attribute__((address_space(3))) void*)(KsB + buf * 8192 + w * 2048 + half * 1024),
                                       16, 0, 0);
      const unsigned short* gv = VT + (size_t)(hoff + srow) * NROWS + rowB + kb2 + 8 * sgr;
      __builtin_amdgcn_global_load_lds((__attribute__((address_space(1))) void*)gv,
                                       (__attribute__((address_space(3))) void*)(VtB + buf * 8192 + w * 2048 + half * 1024),
                                       16, 0, 0);
    }
  };

  // Q fragments (registers for the whole block): lane lr -> q row, lk -> dk chunk
  bf16x8 qf[2][2];
#pragma unroll
  for (int g = 0; g < 2; ++g)
#pragma unroll
    for (int kk = 0; kk < 2; ++kk)
      qf[g][kk] = *reinterpret_cast<const bf16x8*>(
          QKV + (rowB + qw + 16 * g + lr) * QSTR + hoff + 32 * kk + 8 * lk);

  f32x4 oacc[2][4] = {};
  float mrun[2] = {-1e30f, -1e30f};
  float lrun[2] = {0.0f, 0.0f};

  const int ktmax = (qbase + 127) >> 6;
  stage(0, 0);
  for (int kt = 0; kt <= ktmax; ++kt) {
    const int kbase = kt * 64;
    const int cur   = kt & 1;
    __syncthreads();                       // drains vmcnt -> buf cur ready
    if (kt < ktmax) stage(cur ^ 1, kbase + 64);   // prefetch overlaps compute below
    if (kbase > qw + 31) continue;         // fully masked for this wave

    const char* Kc = KsB + cur * 8192;
    const char* Vc = VtB + cur * 8192;

    // ---- QK^T: S^T[k][q], 64k x 16q per group ----
    f32x4 sacc[2][4] = {};
#pragma unroll
    for (int tt = 0; tt < 4; ++tt) {
      bf16x8 kf0 = *reinterpret_cast<const bf16x8*>(Kc + (16 * tt + lr) * 128 + 16 * ((lk + 0) ^ (lr & 7)));
      bf16x8 kf1 = *reinterpret_cast<const bf16x8*>(Kc + (16 * tt + lr) * 128 + 16 * ((lk + 4) ^ (lr & 7)));
#pragma unroll
      for (int g = 0; g < 2; ++g) {
        sacc[g][tt] = __builtin_amdgcn_mfma_f32_16x16x32_bf16(kf0, qf[g][0], sacc[g][tt], 0, 0, 0);
        sacc[g][tt] = __builtin_amdgcn_mfma_f32_16x16x32_bf16(kf1, qf[g][1], sacc[g][tt], 0, 0, 0);
      }
    }

    // ---- softmax per q-group, pack P into LDS ----
#pragma unroll
    for (int g = 0; g < 2; ++g) {
      const int qg = qw + 16 * g + lr;
      float s[4][4];
      if (kbase + 63 > qw + 16 * g) {
#pragma unroll
        for (int tt = 0; tt < 4; ++tt)
#pragma unroll
          for (int r = 0; r < 4; ++r) {
            const int kg = kbase + 16 * tt + 4 * lk + r;
            s[tt][r] = (kg > qg) ? -1e30f : sacc[g][tt][r] * 0.125f;
          }
      } else {
#pragma unroll
        for (int tt = 0; tt < 4; ++tt)
#pragma unroll
          for (int r = 0; r < 4; ++r) s[tt][r] = sacc[g][tt][r] * 0.125f;
      }
      float tm = s[0][0];
#pragma unroll
      for (int tt = 0; tt < 4; ++tt)
#pragma unroll
        for (int r = 0; r < 4; ++r) tm = fmaxf(tm, s[tt][r]);
      tm = fmaxf(tm, __shfl_xor(tm, 16));
      tm = fmaxf(tm, __shfl_xor(tm, 32));
      const float mnew  = fmaxf(mrun[g], tm);
      const float alpha = __expf(mrun[g] - mnew);
      mrun[g] = mnew;
      float ts = 0.0f;
      unsigned short pb[4][4];
#pragma unroll
      for (int tt = 0; tt < 4; ++tt)
#pragma unroll
        for (int r = 0; r < 4; ++r) {
          const float p = __expf(s[tt][r] - mnew);
          ts += p;
          pb[tt][r] = f2bf(p);
        }
      ts += __shfl_xor(ts, 16);
      ts += __shfl_xor(ts, 32);
      lrun[g] = lrun[g] * alpha + ts;
#pragma unroll
      for (int r = 0; r < 4; ++r) {
        const float ar = __shfl(alpha, 4 * lk + r);
#pragma unroll
        for (int dn = 0; dn < 4; ++dn) oacc[g][dn][r] *= ar;
      }
#pragma unroll
      for (int tt = 0; tt < 4; ++tt) {
        u16x4 pw = {pb[tt][0], pb[tt][1], pb[tt][2], pb[tt][3]};
        *reinterpret_cast<u16x4*>(
            PsB + (16 * g + lr) * 128 + ((32 * tt + 8 * lk) ^ (16 * (lr & 7)))) = pw;
      }
    }

    // order P stores before the TBAA-distinct typed re-read below
    asm volatile("" ::: "memory");

    // ---- PV: O[q][d] += P[q][k] V[k][d] ----
#pragma unroll
    for (int kk = 0; kk < 2; ++kk) {
      bf16x8 pa[2];
#pragma unroll
      for (int g = 0; g < 2; ++g)
        pa[g] = *reinterpret_cast<const bf16x8*>(
            PsB + (16 * g + lr) * 128 + ((64 * kk + 16 * lk) ^ (16 * (lr & 7))));
#pragma unroll
      for (int dn = 0; dn < 4; ++dn) {
        bf16x8 vf = *reinterpret_cast<const bf16x8*>(
            Vc + (16 * dn + lr) * 128 + 16 * ((4 * kk + lk) ^ (lr & 7)));
        oacc[0][dn] = __builtin_amdgcn_mfma_f32_16x16x32_bf16(pa[0], vf, oacc[0][dn], 0, 0, 0);
        oacc[1][dn] = __builtin_amdgcn_mfma_f32_16x16x32_bf16(pa[1], vf, oacc[1][dn], 0, 0, 0);
      }
    }
  }

  // ---- epilogue: O / l ----
#pragma unroll
  for (int g = 0; g < 2; ++g) {
#pragma unroll
    for (int r = 0; r < 4; ++r) {
      const float li = 1.0f / __shfl(lrun[g], 4 * lk + r);
      const size_t row = rowB + qw + 16 * g + 4 * lk + r;
#pragma unroll
      for (int dn = 0; dn < 4; ++dn)
        O[row * DM + hoff + 16 * dn + lr] = f2bf(oacc[g][dn][r] * li);
    }
  }
}

// ---------------- launch ----------------
extern "C" void kernel_launch(void* const* d_in, const int* in_sizes, int n_in,
                              void* d_out, int out_size, void* d_ws, size_t ws_size,
                              hipStream_t stream) {
  const float* x   = (const float*)d_in[0];
  const float* ln1 = (const float*)d_in[1];
  const float* ln2 = (const float*)d_in[2];
  const float* wq  = (const float*)d_in[3];
  const float* wk  = (const float*)d_in[4];
  const float* wv  = (const float*)d_in[5];
  const float* wo  = (const float*)d_in[6];
  const float* w1  = (const float*)d_in[7];
  const float* w2  = (const float*)d_in[8];

  char* ws = (char*)d_ws;
  size_t off = 0;
  auto take = [&](size_t bytes) { void* p = ws + off; off += bytes; return p; };
  unsigned short* wqkvb = (unsigned short*)take((size_t)3 * DM * DM * 2);  // 6 MB
  unsigned short* wob   = (unsigned short*)take((size_t)DM * DM * 2);      // 2 MB
  unsigned short* w1b   = (unsigned short*)take((size_t)DFF * DM * 2);     // 8 MB
  unsigned short* w2b   = (unsigned short*)take((size_t)DM * DFF * 2);     // 8 MB
  unsigned short* qkv   = (unsigned short*)take((size_t)NROWS * 3 * DM * 2); // 48 MB
  unsigned short* xn    = (unsigned short*)take((size_t)NROWS * DM * 2);   // 16 MB (ln1 out, reused attn-out)
  unsigned short* hb    = (unsigned short*)take((size_t)NROWS * DFF * 2);  // 64 MB
  // aliases (regions dead by the time the alias is written):
  unsigned short* yn  = qkv;                                  // ln2 out: qkv dead after attn
  float*          yb  = (float*)(qkv + (size_t)NROWS * DM);   // fp32 residual y (32 MB)
  unsigned short* vtb = hb;                                   // V^T [DM][NROWS] (16 MB): hb written after attn

  auto cvt = [&](const float* src, unsigned short* dst, size_t n) {
    int n4 = (int)(n / 4);
    k_f2bf<<<dim3((n4 + 255) / 256), dim3(256), 0, stream>>>(src, dst, n4);
  };
  cvt(wq, wqkvb, (size_t)DM * DM);
  cvt(wk, wqkvb + (size_t)DM * DM, (size_t)DM * DM);
  cvt(wv, wqkvb + (size_t)2 * DM * DM, (size_t)DM * DM);
  cvt(wo, wob, (size_t)DM * DM);
  cvt(w1, w1b, (size_t)DFF * DM);
  cvt(w2, w2b, (size_t)DM * DFF);

  k_rmsnorm<<<dim3(NROWS), dim3(256), 0, stream>>>(x, ln1, xn);

  // fused QKV projection: [8192 x 3072] = xn @ wqkv^T
  k_gemm_nt<0><<<dim3(3 * DM / 128, NROWS / 128), dim3(256), 0, stream>>>(
      xn, wqkvb, qkv, nullptr, NROWS, 3 * DM, DM);

  k_vtrans<<<dim3(NROWS / 64, DM / 64), dim3(256), 0, stream>>>(qkv + 2 * DM, QSTR, vtb);

  k_attn<<<dim3(SEQ / 128, HEADS, BATCH), dim3(256), 0, stream>>>(qkv, vtb, xn);

  const dim3 gD(DM / 128, NROWS / 128);    // (8, 64)
  k_gemm_nt<1><<<gD, dim3(256), 0, stream>>>(xn, wob, yb, x, NROWS, DM, DM);

  k_rmsnorm<<<dim3(NROWS), dim3(256), 0, stream>>>(yb, ln2, yn);

  k_gemm_nt<2><<<dim3(DFF / 128, NROWS / 128), dim3(256), 0, stream>>>(yn, w1b, hb, nullptr, NROWS, DFF, DM);
  k_gemm_nt<1><<<gD, dim3(256), 0, stream>>>(hb, w2b, (float*)d_out, yb, NROWS, DM, DFF);
}

// Round 7
// 525.330 us; speedup vs baseline: 1.5050x; 1.0059x over previous
//
#include <hip/hip_runtime.h>

#define DM    1024
#define DFF   4096
#define SEQ   2048
#define BATCH 4
#define NROWS (BATCH * SEQ)   // 8192
#define HEADS 16
#define DKH   64
#define QSTR  (3 * DM)        // fused QKV row stride

typedef __attribute__((ext_vector_type(4))) float          f32x4;
typedef __attribute__((ext_vector_type(8))) __bf16         bf16x8;
typedef __attribute__((ext_vector_type(8))) unsigned short u16x8;
typedef __attribute__((ext_vector_type(4))) unsigned short u16x4;

static __device__ __forceinline__ unsigned short f2bf(float f) {
  unsigned u = __builtin_bit_cast(unsigned, f);
  u += 0x7fffu + ((u >> 16) & 1u);   // round-to-nearest-even
  return (unsigned short)(u >> 16);
}

// ---------------- fp32 -> bf16 weight conversion ----------------
__global__ void k_f2bf(const float* __restrict__ in, unsigned short* __restrict__ out, int n4) {
  int i = blockIdx.x * blockDim.x + threadIdx.x;
  if (i >= n4) return;
  float4 v = reinterpret_cast<const float4*>(in)[i];
  ushort4 o;
  o.x = f2bf(v.x); o.y = f2bf(v.y); o.z = f2bf(v.z); o.w = f2bf(v.w);
  reinterpret_cast<ushort4*>(out)[i] = o;
}

// ---------------- RMSNorm: fp32 in -> bf16 out ----------------
__global__ __launch_bounds__(256) void k_rmsnorm(const float* __restrict__ x,
                                                 const float* __restrict__ w,
                                                 unsigned short* __restrict__ out) {
  const int row = blockIdx.x;
  const float4 v = reinterpret_cast<const float4*>(x + (size_t)row * DM)[threadIdx.x];
  float ss = v.x * v.x + v.y * v.y + v.z * v.z + v.w * v.w;
#pragma unroll
  for (int off = 32; off > 0; off >>= 1) ss += __shfl_down(ss, off);
  __shared__ float red[4];
  if ((threadIdx.x & 63) == 0) red[threadIdx.x >> 6] = ss;
  __syncthreads();
  const float tot  = red[0] + red[1] + red[2] + red[3];
  const float rden = rsqrtf(tot * (1.0f / DM) + 1e-5f);
  const float4 wv = reinterpret_cast<const float4*>(w)[threadIdx.x];
  ushort4 o;
  o.x = f2bf(v.x * wv.x * rden);
  o.y = f2bf(v.y * wv.y * rden);
  o.z = f2bf(v.z * wv.z * rden);
  o.w = f2bf(v.w * wv.w * rden);
  reinterpret_cast<ushort4*>(out + (size_t)row * DM)[threadIdx.x] = o;
}

// ---------------- bf16 transpose: VT[c][r] = V[r][c] (strided src) ----------------
__global__ __launch_bounds__(256) void k_vtrans(const unsigned short* __restrict__ V, int vstr,
                                                unsigned short* __restrict__ VT) {
  __shared__ unsigned short Tl[64][65];   // +1 pad breaks bank conflicts
  const int t  = threadIdx.x;
  const int r0 = blockIdx.x * 64;         // token tile
  const int c0 = blockIdx.y * 64;         // d-model tile
  const int ltr = t >> 3;                 // 0..31
  const int lc  = (t & 7) * 8;
#pragma unroll
  for (int it = 0; it < 2; ++it) {
    const int r = ltr + 32 * it;
    u16x8 v = *reinterpret_cast<const u16x8*>(V + (size_t)(r0 + r) * vstr + c0 + lc);
#pragma unroll
    for (int i = 0; i < 8; ++i) Tl[r][lc + i] = v[i];
  }
  __syncthreads();
#pragma unroll
  for (int it = 0; it < 2; ++it) {
    const int c = ltr + 32 * it;
    u16x8 o;
#pragma unroll
    for (int i = 0; i < 8; ++i) o[i] = Tl[lc + i][c];
    *reinterpret_cast<u16x8*>(VT + (size_t)(c0 + c) * NROWS + r0 + lc) = o;
  }
}

// ---------------- NT GEMM: C(MxN) = A(MxK,bf16) * B(NxK,bf16)^T ----------------
template <int EPI>
__global__ __launch_bounds__(256) void k_gemm_nt(const unsigned short* __restrict__ A,
                                                 const unsigned short* __restrict__ B,
                                                 void* __restrict__ Cv,
                                                 const float* __restrict__ res,
                                                 int M, int N, int K) {
  alignas(16) __shared__ unsigned short As[128 * 32];
  alignas(16) __shared__ unsigned short Bs[128 * 32];
  const int t  = threadIdx.x;
  const int w  = t >> 6;
  const int l  = t & 63;
  const int wr = w >> 1, wc = w & 1;
  const int lr = l & 15, lk = l >> 4;
  const int m0 = blockIdx.y * 128;
  const int n0 = blockIdx.x * 128;

  const int srow = t >> 2;
  const int scol = (t & 3) * 8;

  f32x4 acc[4][4] = {};

  for (int k0 = 0; k0 < K; k0 += 32) {
    __syncthreads();
#pragma unroll
    for (int r = 0; r < 2; ++r) {
      const unsigned short* ga = A + (size_t)(m0 + r * 64 + srow) * K + k0 + scol;
      const unsigned short* gb = B + (size_t)(n0 + r * 64 + srow) * K + k0 + scol;
      __builtin_amdgcn_global_load_lds((__attribute__((address_space(1))) void*)ga,
                                       (__attribute__((address_space(3))) void*)(As + r * 2048 + w * 512),
                                       16, 0, 0);
      __builtin_amdgcn_global_load_lds((__attribute__((address_space(1))) void*)gb,
                                       (__attribute__((address_space(3))) void*)(Bs + r * 2048 + w * 512),
                                       16, 0, 0);
    }
    __syncthreads();

    bf16x8 af[4], bf[4];
#pragma unroll
    for (int m = 0; m < 4; ++m)
      af[m] = *reinterpret_cast<const bf16x8*>(As + (wr * 64 + m * 16 + lr) * 32 + lk * 8);
#pragma unroll
    for (int n = 0; n < 4; ++n)
      bf[n] = *reinterpret_cast<const bf16x8*>(Bs + (wc * 64 + n * 16 + lr) * 32 + lk * 8);
#pragma unroll
    for (int m = 0; m < 4; ++m)
#pragma unroll
      for (int n = 0; n < 4; ++n)
        acc[m][n] = __builtin_amdgcn_mfma_f32_16x16x32_bf16(af[m], bf[n], acc[m][n], 0, 0, 0);
  }

#pragma unroll
  for (int m = 0; m < 4; ++m) {
#pragma unroll
    for (int n = 0; n < 4; ++n) {
#pragma unroll
      for (int r = 0; r < 4; ++r) {
        const size_t row = (size_t)(m0 + wr * 64 + m * 16 + lk * 4 + r);
        const size_t col = (size_t)(n0 + wc * 64 + n * 16 + lr);
        const float a = acc[m][n][r];
        if constexpr (EPI == 0) {
          ((unsigned short*)Cv)[row * N + col] = f2bf(a);
        } else if constexpr (EPI == 1) {
          ((float*)Cv)[row * N + col] = a + res[row * N + col];
        } else {
          const float g = 0.5f * a * (1.0f + erff(a * 0.70710678118f));
          ((unsigned short*)Cv)[row * N + col] = f2bf(g);
        }
      }
    }
  }
}

// ---------------- Flash causal attention (folded q-tile pairs) ----------------
// grid (SEQ/256, HEADS, BATCH) = 512 blocks, 256 threads = 4 waves.
// Each block processes TWO q-tiles: A = qtA*128.., B = (15-qtA)*128.. ; K/V tiles
// are staged ONCE (dbuf) and consumed by both sets -> uniform work per block
// (A-tiles + B-tiles = const) and halved staging traffic. Swapped QK^T
// (S^T = mfma(K,Q)) keeps softmax lane-local; exp2f with folded 0.125*log2e
// scale (v_exp is natively 2^x -> fewer VALU ops, identical numerics); native
// __bf16 casts for P (compiler pairs into v_cvt_pk). P bounced through
// swizzled per-wave LDS with compiler barriers ordering the TBAA-distinct
// write/read pairs (and the A->B buffer reuse).
__global__ __launch_bounds__(256) void k_attn(const unsigned short* __restrict__ QKV,
                                              const unsigned short* __restrict__ VT,
                                              unsigned short* __restrict__ O) {
  const int qtA = blockIdx.x;                       // 0..7
  const int qtB = (int)(SEQ / 128) - 1 - qtA;       // 15..8
  const int h  = blockIdx.y;
  const int b  = blockIdx.z;
  const int t  = threadIdx.x, w = t >> 6, l = t & 63;
  const int lr = l & 15, lk = l >> 4;
  const size_t rowB = (size_t)b * SEQ;
  const int hoff  = h * DKH;
  const int qw2[2] = { qtA * 128 + 32 * w, qtB * 128 + 32 * w };

  // double-buffered: Ks/Vt [2][64 rows][128B], 16B-granule slot = g ^ (row&7)
  alignas(16) __shared__ unsigned short Ks[2][64 * 64];
  alignas(16) __shared__ unsigned short Vt[2][64 * 64];
  // P bounce per wave: [32 q][64 k], granule-swizzled by (q&7)
  alignas(16) __shared__ unsigned short Ps[4][32 * 64];

  char* const KsB = (char*)Ks;
  char* const VtB = (char*)Vt;
  char* const PsB = (char*)(Ps[w]);

  auto stage = [&](int buf, int kb2) {
#pragma unroll
    for (int half = 0; half < 2; ++half) {
      const int srow = w * 16 + half * 8 + (l >> 3);
      const int sgr  = (l & 7) ^ (srow & 7);   // pre-swizzled source granule
      const unsigned short* gk = QKV + (size_t)(rowB + kb2 + srow) * QSTR + DM + hoff + 8 * sgr;
      __builtin_amdgcn_global_load_lds((__attribute__((address_space(1))) void*)gk,
                                       (__attribute__((address_space(3))) void*)(KsB + buf * 8192 + w * 2048 + half * 1024),
                                       16, 0, 0);
      const unsigned short* gv = VT + (size_t)(hoff + srow) * NROWS + rowB + kb2 + 8 * sgr;
      __builtin_amdgcn_global_load_lds((__attribute__((address_space(1))) void*)gv,
                                       (__attribute__((address_space(3))) void*)(VtB + buf * 8192 + w * 2048 + half * 1024),
                                       16, 0, 0);
    }
  };

  // Q fragments for both sets (registers): lane lr -> q row, lk -> dk chunk
  bf16x8 qf[2][2][2];
#pragma unroll
  for (int s = 0; s < 2; ++s)
#pragma unroll
    for (int g = 0; g < 2; ++g)
#pragma unroll
      for (int kk = 0; kk < 2; ++kk)
        qf[s][g][kk] = *reinterpret_cast<const bf16x8*>(
            QKV + (rowB + qw2[s] + 16 * g + lr) * QSTR + hoff + 32 * kk + 8 * lk);

  f32x4 oacc[2][2][4] = {};
  float mrun[2][2] = {{-1e30f, -1e30f}, {-1e30f, -1e30f}};
  float lrun[2][2] = {{0.0f, 0.0f}, {0.0f, 0.0f}};

  const float SCL = 0.18033688011f;   // 0.125 * log2(e): exp(s*0.125) == exp2(s*SCL)

  const int ktmax = (qtB * 128 + 127) >> 6;   // B set spans all staged tiles
  stage(0, 0);
  for (int kt = 0; kt <= ktmax; ++kt) {
    const int kbase = kt * 64;
    const int cur   = kt & 1;
    __syncthreads();                              // drains vmcnt -> buf cur ready
    if (kt < ktmax) stage(cur ^ 1, kbase + 64);   // prefetch overlaps compute
    const char* Kc = KsB + cur * 8192;
    const char* Vc = VtB + cur * 8192;

#pragma unroll
    for (int s = 0; s < 2; ++s) {
      const int qw = qw2[s];
      if (kbase > qw + 31) continue;   // set fully masked for this wave

      // ---- QK^T: S^T[k][q], 64k x 16q per group ----
      f32x4 sacc[2][4] = {};
#pragma unroll
      for (int tt = 0; tt < 4; ++tt) {
        bf16x8 kf0 = *reinterpret_cast<const bf16x8*>(Kc + (16 * tt + lr) * 128 + 16 * ((lk + 0) ^ (lr & 7)));
        bf16x8 kf1 = *reinterpret_cast<const bf16x8*>(Kc + (16 * tt + lr) * 128 + 16 * ((lk + 4) ^ (lr & 7)));
#pragma unroll
        for (int g = 0; g < 2; ++g) {
          sacc[g][tt] = __builtin_amdgcn_mfma_f32_16x16x32_bf16(kf0, qf[s][g][0], sacc[g][tt], 0, 0, 0);
          sacc[g][tt] = __builtin_amdgcn_mfma_f32_16x16x32_bf16(kf1, qf[s][g][1], sacc[g][tt], 0, 0, 0);
        }
      }

      // ---- softmax per q-group (log2 domain), pack P into LDS ----
#pragma unroll
      for (int g = 0; g < 2; ++g) {
        const int qg = qw + 16 * g + lr;
        float sv[4][4];
        if (kbase + 63 > qw + 16 * g) {
#pragma unroll
          for (int tt = 0; tt < 4; ++tt)
#pragma unroll
            for (int r = 0; r < 4; ++r) {
              const int kg = kbase + 16 * tt + 4 * lk + r;
              sv[tt][r] = (kg > qg) ? -1e30f : sacc[g][tt][r] * SCL;
            }
        } else {
#pragma unroll
          for (int tt = 0; tt < 4; ++tt)
#pragma unroll
            for (int r = 0; r < 4; ++r) sv[tt][r] = sacc[g][tt][r] * SCL;
        }
        float tm = sv[0][0];
#pragma unroll
        for (int tt = 0; tt < 4; ++tt)
#pragma unroll
          for (int r = 0; r < 4; ++r) tm = fmaxf(tm, sv[tt][r]);
        tm = fmaxf(tm, __shfl_xor(tm, 16));
        tm = fmaxf(tm, __shfl_xor(tm, 32));
        const float mnew  = fmaxf(mrun[s][g], tm);
        const float alpha = exp2f(mrun[s][g] - mnew);
        mrun[s][g] = mnew;
        float ts = 0.0f;
        unsigned short pb[4][4];
#pragma unroll
        for (int tt = 0; tt < 4; ++tt)
#pragma unroll
          for (int r = 0; r < 4; ++r) {
            const float p = exp2f(sv[tt][r] - mnew);
            ts += p;
            pb[tt][r] = __builtin_bit_cast(unsigned short, static_cast<__bf16>(p));
          }
        ts += __shfl_xor(ts, 16);
        ts += __shfl_xor(ts, 32);
        lrun[s][g] = lrun[s][g] * alpha + ts;
#pragma unroll
        for (int r = 0; r < 4; ++r) {
          const float ar = __shfl(alpha, 4 * lk + r);
#pragma unroll
          for (int dn = 0; dn < 4; ++dn) oacc[s][g][dn][r] *= ar;
        }
#pragma unroll
        for (int tt = 0; tt < 4; ++tt) {
          u16x4 pw = {pb[tt][0], pb[tt][1], pb[tt][2], pb[tt][3]};
          *reinterpret_cast<u16x4*>(
              PsB + (16 * g + lr) * 128 + ((32 * tt + 8 * lk) ^ (16 * (lr & 7)))) = pw;
        }
      }

      // order P stores before the TBAA-distinct typed re-read below
      asm volatile("" ::: "memory");

      // ---- PV: O[q][d] += P[q][k] V[k][d] ----
#pragma unroll
      for (int kk = 0; kk < 2; ++kk) {
        bf16x8 pa[2];
#pragma unroll
        for (int g = 0; g < 2; ++g)
          pa[g] = *reinterpret_cast<const bf16x8*>(
              PsB + (16 * g + lr) * 128 + ((64 * kk + 16 * lk) ^ (16 * (lr & 7))));
#pragma unroll
        for (int dn = 0; dn < 4; ++dn) {
          bf16x8 vf = *reinterpret_cast<const bf16x8*>(
              Vc + (16 * dn + lr) * 128 + 16 * ((4 * kk + lk) ^ (lr & 7)));
          oacc[s][0][dn] = __builtin_amdgcn_mfma_f32_16x16x32_bf16(pa[0], vf, oacc[s][0][dn], 0, 0, 0);
          oacc[s][1][dn] = __builtin_amdgcn_mfma_f32_16x16x32_bf16(pa[1], vf, oacc[s][1][dn], 0, 0, 0);
        }
      }

      // order PV's P reads before the next set's P stores (WAR on Ps)
      asm volatile("" ::: "memory");
    }
  }

  // ---- epilogue: O / l, both sets ----
#pragma unroll
  for (int s = 0; s < 2; ++s)
#pragma unroll
    for (int g = 0; g < 2; ++g)
#pragma unroll
      for (int r = 0; r < 4; ++r) {
        const float li = 1.0f / __shfl(lrun[s][g], 4 * lk + r);
        const size_t row = rowB + qw2[s] + 16 * g + 4 * lk + r;
#pragma unroll
        for (int dn = 0; dn < 4; ++dn)
          O[row * DM + hoff + 16 * dn + lr] = f2bf(oacc[s][g][dn][r] * li);
      }
}

// ---------------- launch ----------------
extern "C" void kernel_launch(void* const* d_in, const int* in_sizes, int n_in,
                              void* d_out, int out_size, void* d_ws, size_t ws_size,
                              hipStream_t stream) {
  const float* x   = (const float*)d_in[0];
  const float* ln1 = (const float*)d_in[1];
  const float* ln2 = (const float*)d_in[2];
  const float* wq  = (const float*)d_in[3];
  const float* wk  = (const float*)d_in[4];
  const float* wv  = (const float*)d_in[5];
  const float* wo  = (const float*)d_in[6];
  const float* w1  = (const float*)d_in[7];
  const float* w2  = (const float*)d_in[8];

  char* ws = (char*)d_ws;
  size_t off = 0;
  auto take = [&](size_t bytes) { void* p = ws + off; off += bytes; return p; };
  unsigned short* wqkvb = (unsigned short*)take((size_t)3 * DM * DM * 2);  // 6 MB
  unsigned short* wob   = (unsigned short*)take((size_t)DM * DM * 2);      // 2 MB
  unsigned short* w1b   = (unsigned short*)take((size_t)DFF * DM * 2);     // 8 MB
  unsigned short* w2b   = (unsigned short*)take((size_t)DM * DFF * 2);     // 8 MB
  unsigned short* qkv   = (unsigned short*)take((size_t)NROWS * 3 * DM * 2); // 48 MB
  unsigned short* xn    = (unsigned short*)take((size_t)NROWS * DM * 2);   // 16 MB (ln1 out, reused attn-out)
  unsigned short* hb    = (unsigned short*)take((size_t)NROWS * DFF * 2);  // 64 MB
  // aliases (regions dead by the time the alias is written):
  unsigned short* yn  = qkv;                                  // ln2 out: qkv dead after attn
  float*          yb  = (float*)(qkv + (size_t)NROWS * DM);   // fp32 residual y (32 MB)
  unsigned short* vtb = hb;                                   // V^T [DM][NROWS] (16 MB): hb written after attn

  auto cvt = [&](const float* src, unsigned short* dst, size_t n) {
    int n4 = (int)(n / 4);
    k_f2bf<<<dim3((n4 + 255) / 256), dim3(256), 0, stream>>>(src, dst, n4);
  };
  cvt(wq, wqkvb, (size_t)DM * DM);
  cvt(wk, wqkvb + (size_t)DM * DM, (size_t)DM * DM);
  cvt(wv, wqkvb + (size_t)2 * DM * DM, (size_t)DM * DM);
  cvt(wo, wob, (size_t)DM * DM);
  cvt(w1, w1b, (size_t)DFF * DM);
  cvt(w2, w2b, (size_t)DM * DFF);

  k_rmsnorm<<<dim3(NROWS), dim3(256), 0, stream>>>(x, ln1, xn);

  // fused QKV projection: [8192 x 3072] = xn @ wqkv^T
  k_gemm_nt<0><<<dim3(3 * DM / 128, NROWS / 128), dim3(256), 0, stream>>>(
      xn, wqkvb, qkv, nullptr, NROWS, 3 * DM, DM);

  k_vtrans<<<dim3(NROWS / 64, DM / 64), dim3(256), 0, stream>>>(qkv + 2 * DM, QSTR, vtb);

  k_attn<<<dim3(SEQ / 256, HEADS, BATCH), dim3(256), 0, stream>>>(qkv, vtb, xn);

  const dim3 gD(DM / 128, NROWS / 128);    // (8, 64)
  k_gemm_nt<1><<<gD, dim3(256), 0, stream>>>(xn, wob, yb, x, NROWS, DM, DM);

  k_rmsnorm<<<dim3(NROWS), dim3(256), 0, stream>>>(yb, ln2, yn);

  k_gemm_nt<2><<<dim3(DFF / 128, NROWS / 128), dim3(256), 0, stream>>>(yn, w1b, hb, nullptr, NROWS, DFF, DM);
  k_gemm_nt<1><<<gD, dim3(256), 0, stream>>>(hb, w2b, (float*)d_out, yb, NROWS, DM, DFF);
}

// Round 8
// 458.898 us; speedup vs baseline: 1.7229x; 1.1448x over previous
//
#include <hip/hip_runtime.h>

#define DM    1024
#define DFF   4096
#define SEQ   2048
#define BATCH 4
#define NROWS (BATCH * SEQ)   // 8192
#define HEADS 16
#define DKH   64
#define QSTR  (3 * DM)        // fused QKV row stride

typedef __attribute__((ext_vector_type(4))) float          f32x4;
typedef __attribute__((ext_vector_type(8))) __bf16         bf16x8;
typedef __attribute__((ext_vector_type(8))) unsigned short u16x8;
typedef __attribute__((ext_vector_type(4))) unsigned short u16x4;

static __device__ __forceinline__ unsigned short f2bf(float f) {
  unsigned u = __builtin_bit_cast(unsigned, f);
  u += 0x7fffu + ((u >> 16) & 1u);   // round-to-nearest-even
  return (unsigned short)(u >> 16);
}

// ---------------- fp32 -> bf16 weight conversion ----------------
__global__ void k_f2bf(const float* __restrict__ in, unsigned short* __restrict__ out, int n4) {
  int i = blockIdx.x * blockDim.x + threadIdx.x;
  if (i >= n4) return;
  float4 v = reinterpret_cast<const float4*>(in)[i];
  ushort4 o;
  o.x = f2bf(v.x); o.y = f2bf(v.y); o.z = f2bf(v.z); o.w = f2bf(v.w);
  reinterpret_cast<ushort4*>(out)[i] = o;
}

// ---------------- RMSNorm: fp32 in -> bf16 out ----------------
__global__ __launch_bounds__(256) void k_rmsnorm(const float* __restrict__ x,
                                                 const float* __restrict__ w,
                                                 unsigned short* __restrict__ out) {
  const int row = blockIdx.x;
  const float4 v = reinterpret_cast<const float4*>(x + (size_t)row * DM)[threadIdx.x];
  float ss = v.x * v.x + v.y * v.y + v.z * v.z + v.w * v.w;
#pragma unroll
  for (int off = 32; off > 0; off >>= 1) ss += __shfl_down(ss, off);
  __shared__ float red[4];
  if ((threadIdx.x & 63) == 0) red[threadIdx.x >> 6] = ss;
  __syncthreads();
  const float tot  = red[0] + red[1] + red[2] + red[3];
  const float rden = rsqrtf(tot * (1.0f / DM) + 1e-5f);
  const float4 wv = reinterpret_cast<const float4*>(w)[threadIdx.x];
  ushort4 o;
  o.x = f2bf(v.x * wv.x * rden);
  o.y = f2bf(v.y * wv.y * rden);
  o.z = f2bf(v.z * wv.z * rden);
  o.w = f2bf(v.w * wv.w * rden);
  reinterpret_cast<ushort4*>(out + (size_t)row * DM)[threadIdx.x] = o;
}

// ---------------- bf16 transpose: VT[c][r] = V[r][c] (strided src) ----------------
__global__ __launch_bounds__(256) void k_vtrans(const unsigned short* __restrict__ V, int vstr,
                                                unsigned short* __restrict__ VT) {
  __shared__ unsigned short Tl[64][65];   // +1 pad breaks bank conflicts
  const int t  = threadIdx.x;
  const int r0 = blockIdx.x * 64;         // token tile
  const int c0 = blockIdx.y * 64;         // d-model tile
  const int ltr = t >> 3;                 // 0..31
  const int lc  = (t & 7) * 8;
#pragma unroll
  for (int it = 0; it < 2; ++it) {
    const int r = ltr + 32 * it;
    u16x8 v = *reinterpret_cast<const u16x8*>(V + (size_t)(r0 + r) * vstr + c0 + lc);
#pragma unroll
    for (int i = 0; i < 8; ++i) Tl[r][lc + i] = v[i];
  }
  __syncthreads();
#pragma unroll
  for (int it = 0; it < 2; ++it) {
    const int c = ltr + 32 * it;
    u16x8 o;
#pragma unroll
    for (int i = 0; i < 8; ++i) o[i] = Tl[lc + i][c];
    *reinterpret_cast<u16x8*>(VT + (size_t)(c0 + c) * NROWS + r0 + lc) = o;
  }
}

// ---------------- NT GEMM: C(MxN) = A(MxK,bf16) * B(NxK,bf16)^T ----------------
// XCD-aware bijective block swizzle (T1): all grids here have nwg % 8 == 0.
template <int EPI>
__global__ __launch_bounds__(256) void k_gemm_nt(const unsigned short* __restrict__ A,
                                                 const unsigned short* __restrict__ B,
                                                 void* __restrict__ Cv,
                                                 const float* __restrict__ res,
                                                 int M, int N, int K) {
  alignas(16) __shared__ unsigned short As[128 * 32];
  alignas(16) __shared__ unsigned short Bs[128 * 32];
  const int t  = threadIdx.x;
  const int w  = t >> 6;
  const int l  = t & 63;
  const int wr = w >> 1, wc = w & 1;
  const int lr = l & 15, lk = l >> 4;

  const unsigned bid = blockIdx.y * gridDim.x + blockIdx.x;
  const unsigned cpx = (gridDim.x * gridDim.y) >> 3;
  const unsigned sw  = (bid & 7) * cpx + (bid >> 3);
  const int m0 = (int)(sw / gridDim.x) * 128;
  const int n0 = (int)(sw % gridDim.x) * 128;

  const int srow = t >> 2;
  const int scol = (t & 3) * 8;

  f32x4 acc[4][4] = {};

  for (int k0 = 0; k0 < K; k0 += 32) {
    __syncthreads();
#pragma unroll
    for (int r = 0; r < 2; ++r) {
      const unsigned short* ga = A + (size_t)(m0 + r * 64 + srow) * K + k0 + scol;
      const unsigned short* gb = B + (size_t)(n0 + r * 64 + srow) * K + k0 + scol;
      __builtin_amdgcn_global_load_lds((__attribute__((address_space(1))) void*)ga,
                                       (__attribute__((address_space(3))) void*)(As + r * 2048 + w * 512),
                                       16, 0, 0);
      __builtin_amdgcn_global_load_lds((__attribute__((address_space(1))) void*)gb,
                                       (__attribute__((address_space(3))) void*)(Bs + r * 2048 + w * 512),
                                       16, 0, 0);
    }
    __syncthreads();

    bf16x8 af[4], bf[4];
#pragma unroll
    for (int m = 0; m < 4; ++m)
      af[m] = *reinterpret_cast<const bf16x8*>(As + (wr * 64 + m * 16 + lr) * 32 + lk * 8);
#pragma unroll
    for (int n = 0; n < 4; ++n)
      bf[n] = *reinterpret_cast<const bf16x8*>(Bs + (wc * 64 + n * 16 + lr) * 32 + lk * 8);
#pragma unroll
    for (int m = 0; m < 4; ++m)
#pragma unroll
      for (int n = 0; n < 4; ++n)
        acc[m][n] = __builtin_amdgcn_mfma_f32_16x16x32_bf16(af[m], bf[n], acc[m][n], 0, 0, 0);
  }

#pragma unroll
  for (int m = 0; m < 4; ++m) {
#pragma unroll
    for (int n = 0; n < 4; ++n) {
#pragma unroll
      for (int r = 0; r < 4; ++r) {
        const size_t row = (size_t)(m0 + wr * 64 + m * 16 + lk * 4 + r);
        const size_t col = (size_t)(n0 + wc * 64 + n * 16 + lr);
        const float a = acc[m][n][r];
        if constexpr (EPI == 0) {
          ((unsigned short*)Cv)[row * N + col] = f2bf(a);
        } else if constexpr (EPI == 1) {
          ((float*)Cv)[row * N + col] = a + res[row * N + col];
        } else {
          const float g = 0.5f * a * (1.0f + erff(a * 0.70710678118f));
          ((unsigned short*)Cv)[row * N + col] = f2bf(g);
        }
      }
    }
  }
}

// ---------------- Flash causal attention (folded q-pairs, set-parallel phases) ----------------
// grid (8, 16, 4); block index remap puts the 8 q-pair blocks that share one
// (b,h)'s K/V stripe on the SAME XCD (bid%8 == blockIdx.x is XCD-invariant for
// fixed x), so K/V is served from L2 after the first block touches it.
// Per k-tile: QK^T for BOTH sets (K-fragments loaded once) -> softmax both sets
// (independent P buffers, defer-max skips the O-rescale when the running max
// doesn't grow by >8 log2-units) -> one compiler barrier -> PV both sets
// (V-fragments loaded once). Sets are fully independent so their MFMA/VALU
// chains interleave. K/V double-buffered via global_load_lds (2 loads per wave
// per buffer: 1 load = 64 lanes x 16B = 1024B, wave region = 2048B).
__global__ __launch_bounds__(256, 2) void k_attn(const unsigned short* __restrict__ QKV,
                                                 const unsigned short* __restrict__ VT,
                                                 unsigned short* __restrict__ O) {
  const int qtA = blockIdx.y & 7;                   // 0..7
  const int qtB = (int)(SEQ / 128) - 1 - qtA;       // 15..8
  const int h   = blockIdx.x + 8 * (blockIdx.y >> 3);
  const int b   = blockIdx.z;
  const int t  = threadIdx.x, w = t >> 6, l = t & 63;
  const int lr = l & 15, lk = l >> 4;
  const size_t rowB = (size_t)b * SEQ;
  const int hoff  = h * DKH;
  const int qw2[2] = { qtA * 128 + 32 * w, qtB * 128 + 32 * w };

  // double-buffered: Ks/Vt [2][64 rows][128B], 16B-granule slot = g ^ (row&7)
  alignas(16) __shared__ unsigned short Ks[2][64 * 64];   // 16 KB
  alignas(16) __shared__ unsigned short Vt[2][64 * 64];   // 16 KB
  // P bounce per (set, wave): [32 q][64 k], granule-swizzled by (q&7)
  alignas(16) __shared__ unsigned short Ps[2][4][32 * 64]; // 32 KB

  char* const KsB = (char*)Ks;
  char* const VtB = (char*)Vt;

  auto stage = [&](int buf, int kb2) {
#pragma unroll
    for (int half = 0; half < 2; ++half) {
      const int srow = w * 16 + half * 8 + (l >> 3);
      const int sgr  = (l & 7) ^ (srow & 7);   // pre-swizzled source granule
      const unsigned short* gk = QKV + (size_t)(rowB + kb2 + srow) * QSTR + DM + hoff + 8 * sgr;
      __builtin_amdgcn_global_load_lds((__attribute__((address_space(1))) void*)gk,
                                       (__attribute__((address_space(3))) void*)(KsB + buf * 8192 + w * 2048 + half * 1024),
                                       16, 0, 0);
      const unsigned short* gv = VT + (size_t)(hoff + srow) * NROWS + rowB + kb2 + 8 * sgr;
      __builtin_amdgcn_global_load_lds((__attribute__((address_space(1))) void*)gv,
                                       (__attribute__((address_space(3))) void*)(VtB + buf * 8192 + w * 2048 + half * 1024),
                                       16, 0, 0);
    }
  };

  // Q fragments for both sets (registers): lane lr -> q row, lk -> dk chunk
  bf16x8 qf[2][2][2];
#pragma unroll
  for (int s = 0; s < 2; ++s)
#pragma unroll
    for (int g = 0; g < 2; ++g)
#pragma unroll
      for (int kk = 0; kk < 2; ++kk)
        qf[s][g][kk] = *reinterpret_cast<const bf16x8*>(
            QKV + (rowB + qw2[s] + 16 * g + lr) * QSTR + hoff + 32 * kk + 8 * lk);

  f32x4 oacc[2][2][4] = {};
  float mrun[2][2] = {{-1e30f, -1e30f}, {-1e30f, -1e30f}};
  float lrun[2][2] = {{0.0f, 0.0f}, {0.0f, 0.0f}};

  const float SCL = 0.18033688011f;   // 0.125 * log2(e): exp(s*0.125) == exp2(s*SCL)

  const int ktmax = (qtB * 128 + 127) >> 6;   // B set spans all staged tiles
  stage(0, 0);
  for (int kt = 0; kt <= ktmax; ++kt) {
    const int kbase = kt * 64;
    const int cur   = kt & 1;
    __syncthreads();                              // drains vmcnt -> buf cur ready
    if (kt < ktmax) stage(cur ^ 1, kbase + 64);   // prefetch overlaps compute
    const char* Kc = KsB + cur * 8192;
    const char* Vc = VtB + cur * 8192;

    const bool act[2] = { kbase <= qw2[0] + 31, kbase <= qw2[1] + 31 };

    // ---- QK^T both sets: S^T[k][q]; K-fragments loaded once ----
    f32x4 sacc[2][2][4] = {};
#pragma unroll
    for (int tt = 0; tt < 4; ++tt) {
      bf16x8 kf0 = *reinterpret_cast<const bf16x8*>(Kc + (16 * tt + lr) * 128 + 16 * ((lk + 0) ^ (lr & 7)));
      bf16x8 kf1 = *reinterpret_cast<const bf16x8*>(Kc + (16 * tt + lr) * 128 + 16 * ((lk + 4) ^ (lr & 7)));
#pragma unroll
      for (int s = 0; s < 2; ++s) {
        if (!act[s]) continue;
#pragma unroll
        for (int g = 0; g < 2; ++g) {
          sacc[s][g][tt] = __builtin_amdgcn_mfma_f32_16x16x32_bf16(kf0, qf[s][g][0], sacc[s][g][tt], 0, 0, 0);
          sacc[s][g][tt] = __builtin_amdgcn_mfma_f32_16x16x32_bf16(kf1, qf[s][g][1], sacc[s][g][tt], 0, 0, 0);
        }
      }
    }

    // ---- softmax both sets (log2 domain, defer-max), pack P ----
#pragma unroll
    for (int s = 0; s < 2; ++s) {
      if (!act[s]) continue;
      const int qw = qw2[s];
      char* const PsSB = (char*)(Ps[s][w]);
#pragma unroll
      for (int g = 0; g < 2; ++g) {
        const int qg = qw + 16 * g + lr;
        float sv[4][4];
        if (kbase + 63 > qw + 16 * g) {
#pragma unroll
          for (int tt = 0; tt < 4; ++tt)
#pragma unroll
            for (int r = 0; r < 4; ++r) {
              const int kg = kbase + 16 * tt + 4 * lk + r;
              sv[tt][r] = (kg > qg) ? -1e30f : sacc[s][g][tt][r] * SCL;
            }
        } else {
#pragma unroll
          for (int tt = 0; tt < 4; ++tt)
#pragma unroll
            for (int r = 0; r < 4; ++r) sv[tt][r] = sacc[s][g][tt][r] * SCL;
        }
        float tm = sv[0][0];
#pragma unroll
        for (int tt = 0; tt < 4; ++tt)
#pragma unroll
          for (int r = 0; r < 4; ++r) tm = fmaxf(tm, sv[tt][r]);
        tm = fmaxf(tm, __shfl_xor(tm, 16));
        tm = fmaxf(tm, __shfl_xor(tm, 32));
        float mref = mrun[s][g];
        if (__any(tm > mref + 8.0f)) {            // defer-max: rescale only on real growth
          const float mnew  = fmaxf(mref, tm);
          const float alpha = exp2f(mref - mnew);
#pragma unroll
          for (int r = 0; r < 4; ++r) {
            const float ar = __shfl(alpha, 4 * lk + r);
#pragma unroll
            for (int dn = 0; dn < 4; ++dn) oacc[s][g][dn][r] *= ar;
          }
          lrun[s][g] *= alpha;
          mrun[s][g] = mnew;
          mref = mnew;
        }
        float ts = 0.0f;
        unsigned short pb[4][4];
#pragma unroll
        for (int tt = 0; tt < 4; ++tt)
#pragma unroll
          for (int r = 0; r < 4; ++r) {
            const float p = exp2f(sv[tt][r] - mref);   // bounded by 2^8
            ts += p;
            pb[tt][r] = __builtin_bit_cast(unsigned short, static_cast<__bf16>(p));
          }
        ts += __shfl_xor(ts, 16);
        ts += __shfl_xor(ts, 32);
        lrun[s][g] += ts;
#pragma unroll
        for (int tt = 0; tt < 4; ++tt) {
          u16x4 pw = {pb[tt][0], pb[tt][1], pb[tt][2], pb[tt][3]};
          *reinterpret_cast<u16x4*>(
              PsSB + (16 * g + lr) * 128 + ((32 * tt + 8 * lk) ^ (16 * (lr & 7)))) = pw;
        }
      }
    }

    // order P stores before the TBAA-distinct typed re-reads below
    asm volatile("" ::: "memory");

    // ---- PV both sets: O[q][d] += P[q][k] V[k][d]; V-fragments loaded once ----
#pragma unroll
    for (int kk = 0; kk < 2; ++kk) {
      bf16x8 vf[4];
#pragma unroll
      for (int dn = 0; dn < 4; ++dn)
        vf[dn] = *reinterpret_cast<const bf16x8*>(
            Vc + (16 * dn + lr) * 128 + 16 * ((4 * kk + lk) ^ (lr & 7)));
#pragma unroll
      for (int s = 0; s < 2; ++s) {
        if (!act[s]) continue;
        char* const PsSB = (char*)(Ps[s][w]);
        bf16x8 pa[2];
#pragma unroll
        for (int g = 0; g < 2; ++g)
          pa[g] = *reinterpret_cast<const bf16x8*>(
              PsSB + (16 * g + lr) * 128 + ((64 * kk + 16 * lk) ^ (16 * (lr & 7))));
#pragma unroll
        for (int dn = 0; dn < 4; ++dn) {
          oacc[s][0][dn] = __builtin_amdgcn_mfma_f32_16x16x32_bf16(pa[0], vf[dn], oacc[s][0][dn], 0, 0, 0);
          oacc[s][1][dn] = __builtin_amdgcn_mfma_f32_16x16x32_bf16(pa[1], vf[dn], oacc[s][1][dn], 0, 0, 0);
        }
      }
    }

    // order PV's P reads before next iteration's P stores (same-wave WAR on Ps)
    asm volatile("" ::: "memory");
  }

  // ---- epilogue: O / l, both sets ----
#pragma unroll
  for (int s = 0; s < 2; ++s)
#pragma unroll
    for (int g = 0; g < 2; ++g)
#pragma unroll
      for (int r = 0; r < 4; ++r) {
        const float li = 1.0f / __shfl(lrun[s][g], 4 * lk + r);
        const size_t row = rowB + qw2[s] + 16 * g + 4 * lk + r;
#pragma unroll
        for (int dn = 0; dn < 4; ++dn)
          O[row * DM + hoff + 16 * dn + lr] = f2bf(oacc[s][g][dn][r] * li);
      }
}

// ---------------- launch ----------------
extern "C" void kernel_launch(void* const* d_in, const int* in_sizes, int n_in,
                              void* d_out, int out_size, void* d_ws, size_t ws_size,
                              hipStream_t stream) {
  const float* x   = (const float*)d_in[0];
  const float* ln1 = (const float*)d_in[1];
  const float* ln2 = (const float*)d_in[2];
  const float* wq  = (const float*)d_in[3];
  const float* wk  = (const float*)d_in[4];
  const float* wv  = (const float*)d_in[5];
  const float* wo  = (const float*)d_in[6];
  const float* w1  = (const float*)d_in[7];
  const float* w2  = (const float*)d_in[8];

  char* ws = (char*)d_ws;
  size_t off = 0;
  auto take = [&](size_t bytes) { void* p = ws + off; off += bytes; return p; };
  unsigned short* wqkvb = (unsigned short*)take((size_t)3 * DM * DM * 2);  // 6 MB
  unsigned short* wob   = (unsigned short*)take((size_t)DM * DM * 2);      // 2 MB
  unsigned short* w1b   = (unsigned short*)take((size_t)DFF * DM * 2);     // 8 MB
  unsigned short* w2b   = (unsigned short*)take((size_t)DM * DFF * 2);     // 8 MB
  unsigned short* qkv   = (unsigned short*)take((size_t)NROWS * 3 * DM * 2); // 48 MB
  unsigned short* xn    = (unsigned short*)take((size_t)NROWS * DM * 2);   // 16 MB (ln1 out, reused attn-out)
  unsigned short* hb    = (unsigned short*)take((size_t)NROWS * DFF * 2);  // 64 MB
  // aliases (regions dead by the time the alias is written):
  unsigned short* yn  = qkv;                                  // ln2 out: qkv dead after attn
  float*          yb  = (float*)(qkv + (size_t)NROWS * DM);   // fp32 residual y (32 MB)
  unsigned short* vtb = hb;                                   // V^T [DM][NROWS] (16 MB): hb written after attn

  auto cvt = [&](const float* src, unsigned short* dst, size_t n) {
    int n4 = (int)(n / 4);
    k_f2bf<<<dim3((n4 + 255) / 256), dim3(256), 0, stream>>>(src, dst, n4);
  };
  cvt(wq, wqkvb, (size_t)DM * DM);
  cvt(wk, wqkvb + (size_t)DM * DM, (size_t)DM * DM);
  cvt(wv, wqkvb + (size_t)2 * DM * DM, (size_t)DM * DM);
  cvt(wo, wob, (size_t)DM * DM);
  cvt(w1, w1b, (size_t)DFF * DM);
  cvt(w2, w2b, (size_t)DM * DFF);

  k_rmsnorm<<<dim3(NROWS), dim3(256), 0, stream>>>(x, ln1, xn);

  // fused QKV projection: [8192 x 3072] = xn @ wqkv^T
  k_gemm_nt<0><<<dim3(3 * DM / 128, NROWS / 128), dim3(256), 0, stream>>>(
      xn, wqkvb, qkv, nullptr, NROWS, 3 * DM, DM);

  k_vtrans<<<dim3(NROWS / 64, DM / 64), dim3(256), 0, stream>>>(qkv + 2 * DM, QSTR, vtb);

  k_attn<<<dim3(SEQ / 256, HEADS, BATCH), dim3(256), 0, stream>>>(qkv, vtb, xn);

  const dim3 gD(DM / 128, NROWS / 128);    // (8, 64)
  k_gemm_nt<1><<<gD, dim3(256), 0, stream>>>(xn, wob, yb, x, NROWS, DM, DM);

  k_rmsnorm<<<dim3(NROWS), dim3(256), 0, stream>>>(yb, ln2, yn);

  k_gemm_nt<2><<<dim3(DFF / 128, NROWS / 128), dim3(256), 0, stream>>>(yn, w1b, hb, nullptr, NROWS, DFF, DM);
  k_gemm_nt<1><<<gD, dim3(256), 0, stream>>>(hb, w2b, (float*)d_out, yb, NROWS, DM, DFF);
}

// Round 9
// 422.938 us; speedup vs baseline: 1.8694x; 1.0850x over previous
//
#include <hip/hip_runtime.h>

#define DM    1024
#define DFF   4096
#define SEQ   2048
#define BATCH 4
#define NROWS (BATCH * SEQ)   // 8192
#define HEADS 16
#define DKH   64
#define QSTR  (3 * DM)        // fused QKV row stride

typedef __attribute__((ext_vector_type(4))) float          f32x4;
typedef __attribute__((ext_vector_type(8))) __bf16         bf16x8;
typedef __attribute__((ext_vector_type(8))) unsigned short u16x8;
typedef __attribute__((ext_vector_type(4))) unsigned short u16x4;

static __device__ __forceinline__ unsigned short f2bf(float f) {
  unsigned u = __builtin_bit_cast(unsigned, f);
  u += 0x7fffu + ((u >> 16) & 1u);   // round-to-nearest-even
  return (unsigned short)(u >> 16);
}

// ---------------- fp32 -> bf16 weight conversion ----------------
__global__ void k_f2bf(const float* __restrict__ in, unsigned short* __restrict__ out, int n4) {
  int i = blockIdx.x * blockDim.x + threadIdx.x;
  if (i >= n4) return;
  float4 v = reinterpret_cast<const float4*>(in)[i];
  ushort4 o;
  o.x = f2bf(v.x); o.y = f2bf(v.y); o.z = f2bf(v.z); o.w = f2bf(v.w);
  reinterpret_cast<ushort4*>(out)[i] = o;
}

// ---------------- RMSNorm: fp32 in -> bf16 out ----------------
__global__ __launch_bounds__(256) void k_rmsnorm(const float* __restrict__ x,
                                                 const float* __restrict__ w,
                                                 unsigned short* __restrict__ out) {
  const int row = blockIdx.x;
  const float4 v = reinterpret_cast<const float4*>(x + (size_t)row * DM)[threadIdx.x];
  float ss = v.x * v.x + v.y * v.y + v.z * v.z + v.w * v.w;
#pragma unroll
  for (int off = 32; off > 0; off >>= 1) ss += __shfl_down(ss, off);
  __shared__ float red[4];
  if ((threadIdx.x & 63) == 0) red[threadIdx.x >> 6] = ss;
  __syncthreads();
  const float tot  = red[0] + red[1] + red[2] + red[3];
  const float rden = rsqrtf(tot * (1.0f / DM) + 1e-5f);
  const float4 wv = reinterpret_cast<const float4*>(w)[threadIdx.x];
  ushort4 o;
  o.x = f2bf(v.x * wv.x * rden);
  o.y = f2bf(v.y * wv.y * rden);
  o.z = f2bf(v.z * wv.z * rden);
  o.w = f2bf(v.w * wv.w * rden);
  reinterpret_cast<ushort4*>(out + (size_t)row * DM)[threadIdx.x] = o;
}

// ---------------- bf16 transpose: VT[c][r] = V[r][c] (strided src) ----------------
__global__ __launch_bounds__(256) void k_vtrans(const unsigned short* __restrict__ V, int vstr,
                                                unsigned short* __restrict__ VT) {
  __shared__ unsigned short Tl[64][65];   // +1 pad breaks bank conflicts
  const int t  = threadIdx.x;
  const int r0 = blockIdx.x * 64;         // token tile
  const int c0 = blockIdx.y * 64;         // d-model tile
  const int ltr = t >> 3;                 // 0..31
  const int lc  = (t & 7) * 8;
#pragma unroll
  for (int it = 0; it < 2; ++it) {
    const int r = ltr + 32 * it;
    u16x8 v = *reinterpret_cast<const u16x8*>(V + (size_t)(r0 + r) * vstr + c0 + lc);
#pragma unroll
    for (int i = 0; i < 8; ++i) Tl[r][lc + i] = v[i];
  }
  __syncthreads();
#pragma unroll
  for (int it = 0; it < 2; ++it) {
    const int c = ltr + 32 * it;
    u16x8 o;
#pragma unroll
    for (int i = 0; i < 8; ++i) o[i] = Tl[lc + i][c];
    *reinterpret_cast<u16x8*>(VT + (size_t)(c0 + c) * NROWS + r0 + lc) = o;
  }
}

// ---------------- NT GEMM: C(MxN) = A(MxK,bf16) * B(NxK,bf16)^T ----------------
// 128x128 tile, 4 waves. Double-buffered 2-phase K-loop (one barrier/iter;
// prefetch of tile k+1 issued before compute of tile k so the vmcnt drain at
// the next barrier is covered by compute). A/B LDS tiles use a 16B-granule
// XOR swizzle (slot = lk ^ (row&3)) with pre-swizzled global source (linear
// LDS dest, same pattern as attention's Ks) -> 8-way ds_read_b128 conflicts
// drop to 4-way. XCD-aware bijective block swizzle (grids here are %8==0).
template <int EPI>
__global__ __launch_bounds__(256) void k_gemm_nt(const unsigned short* __restrict__ A,
                                                 const unsigned short* __restrict__ B,
                                                 void* __restrict__ Cv,
                                                 const float* __restrict__ res,
                                                 int M, int N, int K) {
  alignas(16) __shared__ unsigned short As[2][128 * 32];
  alignas(16) __shared__ unsigned short Bs[2][128 * 32];
  const int t  = threadIdx.x;
  const int w  = t >> 6;
  const int l  = t & 63;
  const int wr = w >> 1, wc = w & 1;
  const int lr = l & 15, lk = l >> 4;

  const unsigned bid = blockIdx.y * gridDim.x + blockIdx.x;
  const unsigned cpx = (gridDim.x * gridDim.y) >> 3;
  const unsigned sw  = (bid & 7) * cpx + (bid >> 3);
  const int m0 = (int)(sw / gridDim.x) * 128;
  const int n0 = (int)(sw % gridDim.x) * 128;

  const int srow = t >> 2;                    // 0..63 (row within 64-row half)
  const int sgr  = (t & 3) ^ (srow & 3);      // pre-swizzled source granule

  auto stage = [&](int buf, int k0) {
#pragma unroll
    for (int r = 0; r < 2; ++r) {
      const unsigned short* ga = A + (size_t)(m0 + r * 64 + srow) * K + k0 + 8 * sgr;
      const unsigned short* gb = B + (size_t)(n0 + r * 64 + srow) * K + k0 + 8 * sgr;
      __builtin_amdgcn_global_load_lds((__attribute__((address_space(1))) void*)ga,
                                       (__attribute__((address_space(3))) void*)(&As[buf][r * 2048 + w * 512]),
                                       16, 0, 0);
      __builtin_amdgcn_global_load_lds((__attribute__((address_space(1))) void*)gb,
                                       (__attribute__((address_space(3))) void*)(&Bs[buf][r * 2048 + w * 512]),
                                       16, 0, 0);
    }
  };

  f32x4 acc[4][4] = {};

  stage(0, 0);
  const int nIt = K >> 5;
  for (int it = 0; it < nIt; ++it) {
    const int buf = it & 1;
    __syncthreads();                          // drains vmcnt -> buf ready; WAR-safe
    if (it + 1 < nIt) stage(buf ^ 1, (it + 1) << 5);

    bf16x8 af[4], bf[4];
#pragma unroll
    for (int m = 0; m < 4; ++m)
      af[m] = *reinterpret_cast<const bf16x8*>(
          &As[buf][(wr * 64 + m * 16 + lr) * 32 + 8 * (lk ^ (lr & 3))]);
#pragma unroll
    for (int n = 0; n < 4; ++n)
      bf[n] = *reinterpret_cast<const bf16x8*>(
          &Bs[buf][(wc * 64 + n * 16 + lr) * 32 + 8 * (lk ^ (lr & 3))]);
#pragma unroll
    for (int m = 0; m < 4; ++m)
#pragma unroll
      for (int n = 0; n < 4; ++n)
        acc[m][n] = __builtin_amdgcn_mfma_f32_16x16x32_bf16(af[m], bf[n], acc[m][n], 0, 0, 0);
  }

#pragma unroll
  for (int m = 0; m < 4; ++m) {
#pragma unroll
    for (int n = 0; n < 4; ++n) {
#pragma unroll
      for (int r = 0; r < 4; ++r) {
        const size_t row = (size_t)(m0 + wr * 64 + m * 16 + lk * 4 + r);
        const size_t col = (size_t)(n0 + wc * 64 + n * 16 + lr);
        const float a = acc[m][n][r];
        if constexpr (EPI == 0) {
          ((unsigned short*)Cv)[row * N + col] = f2bf(a);
        } else if constexpr (EPI == 1) {
          ((float*)Cv)[row * N + col] = a + res[row * N + col];
        } else {
          // GELU, tanh/exp2 form: g = h - h/(exp2(h*(a1+b1*h^2))+1)
          // a1 = 2*log2(e)*sqrt(2/pi), b1 = a1*0.044715; max dev vs erf ~3e-3.
          const float h2 = a * a;
          const float e  = exp2f(a * (2.30221535f + 0.10295355f * h2));
          const float g  = a - a / (e + 1.0f);
          ((unsigned short*)Cv)[row * N + col] = f2bf(g);
        }
      }
    }
  }
}

// ---------------- Flash causal attention (folded q-pairs, set-parallel phases) ----------------
// grid (8, 16, 4); block index remap puts the 8 q-pair blocks that share one
// (b,h)'s K/V stripe on the SAME XCD (bid%8 == blockIdx.x is XCD-invariant for
// fixed x), so K/V is served from L2 after the first block touches it.
// Per k-tile: QK^T for BOTH sets (K-fragments loaded once) -> softmax both sets
// (independent P buffers, defer-max skips the O-rescale when the running max
// doesn't grow by >8 log2-units) -> one compiler barrier -> PV both sets
// (V-fragments loaded once). K/V double-buffered via global_load_lds (2 loads
// per wave per buffer: 1 load = 64 lanes x 16B = 1024B, wave region = 2048B).
__global__ __launch_bounds__(256, 2) void k_attn(const unsigned short* __restrict__ QKV,
                                                 const unsigned short* __restrict__ VT,
                                                 unsigned short* __restrict__ O) {
  const int qtA = blockIdx.y & 7;                   // 0..7
  const int qtB = (int)(SEQ / 128) - 1 - qtA;       // 15..8
  const int h   = blockIdx.x + 8 * (blockIdx.y >> 3);
  const int b   = blockIdx.z;
  const int t  = threadIdx.x, w = t >> 6, l = t & 63;
  const int lr = l & 15, lk = l >> 4;
  const size_t rowB = (size_t)b * SEQ;
  const int hoff  = h * DKH;
  const int qw2[2] = { qtA * 128 + 32 * w, qtB * 128 + 32 * w };

  // double-buffered: Ks/Vt [2][64 rows][128B], 16B-granule slot = g ^ (row&7)
  alignas(16) __shared__ unsigned short Ks[2][64 * 64];   // 16 KB
  alignas(16) __shared__ unsigned short Vt[2][64 * 64];   // 16 KB
  // P bounce per (set, wave): [32 q][64 k], granule-swizzled by (q&7)
  alignas(16) __shared__ unsigned short Ps[2][4][32 * 64]; // 32 KB

  char* const KsB = (char*)Ks;
  char* const VtB = (char*)Vt;

  auto stage = [&](int buf, int kb2) {
#pragma unroll
    for (int half = 0; half < 2; ++half) {
      const int srow = w * 16 + half * 8 + (l >> 3);
      const int sgr  = (l & 7) ^ (srow & 7);   // pre-swizzled source granule
      const unsigned short* gk = QKV + (size_t)(rowB + kb2 + srow) * QSTR + DM + hoff + 8 * sgr;
      __builtin_amdgcn_global_load_lds((__attribute__((address_space(1))) void*)gk,
                                       (__attribute__((address_space(3))) void*)(KsB + buf * 8192 + w * 2048 + half * 1024),
                                       16, 0, 0);
      const unsigned short* gv = VT + (size_t)(hoff + srow) * NROWS + rowB + kb2 + 8 * sgr;
      __builtin_amdgcn_global_load_lds((__attribute__((address_space(1))) void*)gv,
                                       (__attribute__((address_space(3))) void*)(VtB + buf * 8192 + w * 2048 + half * 1024),
                                       16, 0, 0);
    }
  };

  // Q fragments for both sets (registers): lane lr -> q row, lk -> dk chunk
  bf16x8 qf[2][2][2];
#pragma unroll
  for (int s = 0; s < 2; ++s)
#pragma unroll
    for (int g = 0; g < 2; ++g)
#pragma unroll
      for (int kk = 0; kk < 2; ++kk)
        qf[s][g][kk] = *reinterpret_cast<const bf16x8*>(
            QKV + (rowB + qw2[s] + 16 * g + lr) * QSTR + hoff + 32 * kk + 8 * lk);

  f32x4 oacc[2][2][4] = {};
  float mrun[2][2] = {{-1e30f, -1e30f}, {-1e30f, -1e30f}};
  float lrun[2][2] = {{0.0f, 0.0f}, {0.0f, 0.0f}};

  const float SCL = 0.18033688011f;   // 0.125 * log2(e): exp(s*0.125) == exp2(s*SCL)

  const int ktmax = (qtB * 128 + 127) >> 6;   // B set spans all staged tiles
  stage(0, 0);
  for (int kt = 0; kt <= ktmax; ++kt) {
    const int kbase = kt * 64;
    const int cur   = kt & 1;
    __syncthreads();                              // drains vmcnt -> buf cur ready
    if (kt < ktmax) stage(cur ^ 1, kbase + 64);   // prefetch overlaps compute
    const char* Kc = KsB + cur * 8192;
    const char* Vc = VtB + cur * 8192;

    const bool act[2] = { kbase <= qw2[0] + 31, kbase <= qw2[1] + 31 };

    // ---- QK^T both sets: S^T[k][q]; K-fragments loaded once ----
    f32x4 sacc[2][2][4] = {};
#pragma unroll
    for (int tt = 0; tt < 4; ++tt) {
      bf16x8 kf0 = *reinterpret_cast<const bf16x8*>(Kc + (16 * tt + lr) * 128 + 16 * ((lk + 0) ^ (lr & 7)));
      bf16x8 kf1 = *reinterpret_cast<const bf16x8*>(Kc + (16 * tt + lr) * 128 + 16 * ((lk + 4) ^ (lr & 7)));
#pragma unroll
      for (int s = 0; s < 2; ++s) {
        if (!act[s]) continue;
#pragma unroll
        for (int g = 0; g < 2; ++g) {
          sacc[s][g][tt] = __builtin_amdgcn_mfma_f32_16x16x32_bf16(kf0, qf[s][g][0], sacc[s][g][tt], 0, 0, 0);
          sacc[s][g][tt] = __builtin_amdgcn_mfma_f32_16x16x32_bf16(kf1, qf[s][g][1], sacc[s][g][tt], 0, 0, 0);
        }
      }
    }

    // ---- softmax both sets (log2 domain, defer-max), pack P ----
#pragma unroll
    for (int s = 0; s < 2; ++s) {
      if (!act[s]) continue;
      const int qw = qw2[s];
      char* const PsSB = (char*)(Ps[s][w]);
#pragma unroll
      for (int g = 0; g < 2; ++g) {
        const int qg = qw + 16 * g + lr;
        float sv[4][4];
        if (kbase + 63 > qw + 16 * g) {
#pragma unroll
          for (int tt = 0; tt < 4; ++tt)
#pragma unroll
            for (int r = 0; r < 4; ++r) {
              const int kg = kbase + 16 * tt + 4 * lk + r;
              sv[tt][r] = (kg > qg) ? -1e30f : sacc[s][g][tt][r] * SCL;
            }
        } else {
#pragma unroll
          for (int tt = 0; tt < 4; ++tt)
#pragma unroll
            for (int r = 0; r < 4; ++r) sv[tt][r] = sacc[s][g][tt][r] * SCL;
        }
        float tm = sv[0][0];
#pragma unroll
        for (int tt = 0; tt < 4; ++tt)
#pragma unroll
          for (int r = 0; r < 4; ++r) tm = fmaxf(tm, sv[tt][r]);
        tm = fmaxf(tm, __shfl_xor(tm, 16));
        tm = fmaxf(tm, __shfl_xor(tm, 32));
        float mref = mrun[s][g];
        if (__any(tm > mref + 8.0f)) {            // defer-max: rescale only on real growth
          const float mnew  = fmaxf(mref, tm);
          const float alpha = exp2f(mref - mnew);
#pragma unroll
          for (int r = 0; r < 4; ++r) {
            const float ar = __shfl(alpha, 4 * lk + r);
#pragma unroll
            for (int dn = 0; dn < 4; ++dn) oacc[s][g][dn][r] *= ar;
          }
          lrun[s][g] *= alpha;
          mrun[s][g] = mnew;
          mref = mnew;
        }
        float ts = 0.0f;
        unsigned short pb[4][4];
#pragma unroll
        for (int tt = 0; tt < 4; ++tt)
#pragma unroll
          for (int r = 0; r < 4; ++r) {
            const float p = exp2f(sv[tt][r] - mref);   // bounded by 2^8
            ts += p;
            pb[tt][r] = __builtin_bit_cast(unsigned short, static_cast<__bf16>(p));
          }
        ts += __shfl_xor(ts, 16);
        ts += __shfl_xor(ts, 32);
        lrun[s][g] += ts;
#pragma unroll
        for (int tt = 0; tt < 4; ++tt) {
          u16x4 pw = {pb[tt][0], pb[tt][1], pb[tt][2], pb[tt][3]};
          *reinterpret_cast<u16x4*>(
              PsSB + (16 * g + lr) * 128 + ((32 * tt + 8 * lk) ^ (16 * (lr & 7)))) = pw;
        }
      }
    }

    // order P stores before the TBAA-distinct typed re-reads below
    asm volatile("" ::: "memory");

    // ---- PV both sets: O[q][d] += P[q][k] V[k][d]; V-fragments loaded once ----
#pragma unroll
    for (int kk = 0; kk < 2; ++kk) {
      bf16x8 vf[4];
#pragma unroll
      for (int dn = 0; dn < 4; ++dn)
        vf[dn] = *reinterpret_cast<const bf16x8*>(
            Vc + (16 * dn + lr) * 128 + 16 * ((4 * kk + lk) ^ (lr & 7)));
#pragma unroll
      for (int s = 0; s < 2; ++s) {
        if (!act[s]) continue;
        char* const PsSB = (char*)(Ps[s][w]);
        bf16x8 pa[2];
#pragma unroll
        for (int g = 0; g < 2; ++g)
          pa[g] = *reinterpret_cast<const bf16x8*>(
              PsSB + (16 * g + lr) * 128 + ((64 * kk + 16 * lk) ^ (16 * (lr & 7))));
#pragma unroll
        for (int dn = 0; dn < 4; ++dn) {
          oacc[s][0][dn] = __builtin_amdgcn_mfma_f32_16x16x32_bf16(pa[0], vf[dn], oacc[s][0][dn], 0, 0, 0);
          oacc[s][1][dn] = __builtin_amdgcn_mfma_f32_16x16x32_bf16(pa[1], vf[dn], oacc[s][1][dn], 0, 0, 0);
        }
      }
    }

    // order PV's P reads before next iteration's P stores (same-wave WAR on Ps)
    asm volatile("" ::: "memory");
  }

  // ---- epilogue: O / l, both sets ----
#pragma unroll
  for (int s = 0; s < 2; ++s)
#pragma unroll
    for (int g = 0; g < 2; ++g)
#pragma unroll
      for (int r = 0; r < 4; ++r) {
        const float li = 1.0f / __shfl(lrun[s][g], 4 * lk + r);
        const size_t row = rowB + qw2[s] + 16 * g + 4 * lk + r;
#pragma unroll
        for (int dn = 0; dn < 4; ++dn)
          O[row * DM + hoff + 16 * dn + lr] = f2bf(oacc[s][g][dn][r] * li);
      }
}

// ---------------- launch ----------------
extern "C" void kernel_launch(void* const* d_in, const int* in_sizes, int n_in,
                              void* d_out, int out_size, void* d_ws, size_t ws_size,
                              hipStream_t stream) {
  const float* x   = (const float*)d_in[0];
  const float* ln1 = (const float*)d_in[1];
  const float* ln2 = (const float*)d_in[2];
  const float* wq  = (const float*)d_in[3];
  const float* wk  = (const float*)d_in[4];
  const float* wv  = (const float*)d_in[5];
  const float* wo  = (const float*)d_in[6];
  const float* w1  = (const float*)d_in[7];
  const float* w2  = (const float*)d_in[8];

  char* ws = (char*)d_ws;
  size_t off = 0;
  auto take = [&](size_t bytes) { void* p = ws + off; off += bytes; return p; };
  unsigned short* wqkvb = (unsigned short*)take((size_t)3 * DM * DM * 2);  // 6 MB
  unsigned short* wob   = (unsigned short*)take((size_t)DM * DM * 2);      // 2 MB
  unsigned short* w1b   = (unsigned short*)take((size_t)DFF * DM * 2);     // 8 MB
  unsigned short* w2b   = (unsigned short*)take((size_t)DM * DFF * 2);     // 8 MB
  unsigned short* qkv   = (unsigned short*)take((size_t)NROWS * 3 * DM * 2); // 48 MB
  unsigned short* xn    = (unsigned short*)take((size_t)NROWS * DM * 2);   // 16 MB (ln1 out, reused attn-out)
  unsigned short* hb    = (unsigned short*)take((size_t)NROWS * DFF * 2);  // 64 MB
  // aliases (regions dead by the time the alias is written):
  unsigned short* yn  = qkv;                                  // ln2 out: qkv dead after attn
  float*          yb  = (float*)(qkv + (size_t)NROWS * DM);   // fp32 residual y (32 MB)
  unsigned short* vtb = hb;                                   // V^T [DM][NROWS] (16 MB): hb written after attn

  auto cvt = [&](const float* src, unsigned short* dst, size_t n) {
    int n4 = (int)(n / 4);
    k_f2bf<<<dim3((n4 + 255) / 256), dim3(256), 0, stream>>>(src, dst, n4);
  };
  cvt(wq, wqkvb, (size_t)DM * DM);
  cvt(wk, wqkvb + (size_t)DM * DM, (size_t)DM * DM);
  cvt(wv, wqkvb + (size_t)2 * DM * DM, (size_t)DM * DM);
  cvt(wo, wob, (size_t)DM * DM);
  cvt(w1, w1b, (size_t)DFF * DM);
  cvt(w2, w2b, (size_t)DM * DFF);

  k_rmsnorm<<<dim3(NROWS), dim3(256), 0, stream>>>(x, ln1, xn);

  // fused QKV projection: [8192 x 3072] = xn @ wqkv^T
  k_gemm_nt<0><<<dim3(3 * DM / 128, NROWS / 128), dim3(256), 0, stream>>>(
      xn, wqkvb, qkv, nullptr, NROWS, 3 * DM, DM);

  k_vtrans<<<dim3(NROWS / 64, DM / 64), dim3(256), 0, stream>>>(qkv + 2 * DM, QSTR, vtb);

  k_attn<<<dim3(SEQ / 256, HEADS, BATCH), dim3(256), 0, stream>>>(qkv, vtb, xn);

  const dim3 gD(DM / 128, NROWS / 128);    // (8, 64)
  k_gemm_nt<1><<<gD, dim3(256), 0, stream>>>(xn, wob, yb, x, NROWS, DM, DM);

  k_rmsnorm<<<dim3(NROWS), dim3(256), 0, stream>>>(yb, ln2, yn);

  k_gemm_nt<2><<<dim3(DFF / 128, NROWS / 128), dim3(256), 0, stream>>>(yn, w1b, hb, nullptr, NROWS, DFF, DM);
  k_gemm_nt<1><<<gD, dim3(256), 0, stream>>>(hb, w2b, (float*)d_out, yb, NROWS, DM, DFF);
}